// Round 3
// baseline (1235.593 us; speedup 1.0000x reference)
//
#include <hip/hip_runtime.h>
#include <hip/hip_bf16.h>

// Problem constants
#define D_MODEL 256
#define D_INNER 512
#define NHEADS 8
#define HEADDIM 64
#define MDIST 16
#define BB 4
#define LL 2048
#define QQ 300
#define QP 320          // padded Q (5*64; each lane scans 40 n's)
#define NSEG 16
#define SEGLEN 128      // LL / NSEG

typedef unsigned short ushort_t;
typedef __attribute__((ext_vector_type(8))) short bf16x8;
typedef __attribute__((ext_vector_type(4))) float f32x4;

// ---------------------------------------------------------------------------
// Split fp32 -> bf16 hi + bf16 lo (residual). C = Ah*Bh + Ah*Bl + Al*Bh gives
// ~fp32 accuracy (missing Al*Bl term ~2^-18 relative).
// ---------------------------------------------------------------------------
__global__ __launch_bounds__(256) void c_split(const float* __restrict__ in,
                                               ushort_t* __restrict__ hi,
                                               ushort_t* __restrict__ lo, int n) {
    int i = blockIdx.x * 256 + threadIdx.x;
    if (i >= n) return;
    float v = in[i];
    __hip_bfloat16 h = __float2bfloat16(v);
    float hf = __bfloat162float(h);
    __hip_bfloat16 l = __float2bfloat16(v - hf);
    hi[i] = *(ushort_t*)&h;
    lo[i] = *(ushort_t*)&l;
}

// ---------------------------------------------------------------------------
// Split-bf16 MFMA GEMM: C[M,N] = A[M,K] * B[N,K]^T (NT), fp32 out.
// K mult of 32, N mult of 64. Block 256 = 4 waves; block tile 128m x 64n;
// wave tile 32m x 64n. No LDS: frags load 16B contiguous-in-K from global
// (weights L1/L2 resident). mfma_f32_16x16x32_bf16 layout (m89-verified):
//   A[m=lane&15][k=(lane>>4)*8+j]; B[k=(lane>>4)*8+j][n=lane&15];
//   D[row=(lane>>4)*4+r][col=lane&15].
// ---------------------------------------------------------------------------
__global__ __launch_bounds__(256) void gemm_bf16s(const ushort_t* __restrict__ Ah,
                                                  const ushort_t* __restrict__ Al,
                                                  const ushort_t* __restrict__ Bh,
                                                  const ushort_t* __restrict__ Bl,
                                                  float* __restrict__ C,
                                                  int M, int N, int K) {
    int w = threadIdx.x >> 6, lane = threadIdx.x & 63;
    int n0 = blockIdx.x * 64;
    int m0 = blockIdx.y * 128 + w * 32;
    int lm = lane & 15, lk = (lane >> 4) * 8;
    f32x4 acc[2][4];
#pragma unroll
    for (int i = 0; i < 2; i++)
#pragma unroll
        for (int j = 0; j < 4; j++) acc[i][j] = {0.f, 0.f, 0.f, 0.f};

    for (int k0 = 0; k0 < K; k0 += 32) {
        bf16x8 ah[2], al[2], bh[4], blo[4];
#pragma unroll
        for (int mf = 0; mf < 2; mf++) {
            int row = m0 + mf * 16 + lm;
            if (row >= M) row = M - 1;            // safe clamp; epilogue guards
            size_t off = (size_t)row * K + k0 + lk;
            ah[mf] = *(const bf16x8*)(Ah + off);
            al[mf] = *(const bf16x8*)(Al + off);
        }
#pragma unroll
        for (int nf = 0; nf < 4; nf++) {
            int col = n0 + nf * 16 + lm;
            size_t off = (size_t)col * K + k0 + lk;
            bh[nf]  = *(const bf16x8*)(Bh + off);
            blo[nf] = *(const bf16x8*)(Bl + off);
        }
#pragma unroll
        for (int mf = 0; mf < 2; mf++)
#pragma unroll
            for (int nf = 0; nf < 4; nf++) {
                acc[mf][nf] = __builtin_amdgcn_mfma_f32_16x16x32_bf16(ah[mf], bh[nf],  acc[mf][nf], 0, 0, 0);
                acc[mf][nf] = __builtin_amdgcn_mfma_f32_16x16x32_bf16(ah[mf], blo[nf], acc[mf][nf], 0, 0, 0);
                acc[mf][nf] = __builtin_amdgcn_mfma_f32_16x16x32_bf16(al[mf], bh[nf],  acc[mf][nf], 0, 0, 0);
            }
    }
#pragma unroll
    for (int mf = 0; mf < 2; mf++)
#pragma unroll
        for (int nf = 0; nf < 4; nf++)
#pragma unroll
            for (int r = 0; r < 4; r++) {
                int m = m0 + mf * 16 + (lane >> 4) * 4 + r;
                if (m < M) C[(size_t)m * N + n0 + nf * 16 + lm] = acc[mf][nf][r];
            }
}

// ---------------------------------------------------------------------------
// K1b: fp32 bias columns (rows 1024..1033 of W_key) — precision-critical
// (feeds exp(A*dt)). bias10[bl][c] = in_key[bl] . W_key[1024+c]
// ---------------------------------------------------------------------------
__global__ __launch_bounds__(256) void k1b_bias(const float* __restrict__ in_key,
                                                const float* __restrict__ W_key,
                                                float* __restrict__ bias10) {
    int w = threadIdx.x >> 6, lane = threadIdx.x & 63;
    int row = blockIdx.x * 4 + w;
    float4 a = *(const float4*)(in_key + (size_t)row * 256 + lane * 4);
#pragma unroll
    for (int c = 0; c < 10; c++) {
        float4 b = *(const float4*)(W_key + (size_t)(1024 + c) * 256 + lane * 4);
        float t = a.x * b.x + a.y * b.y + a.z * b.z + a.w * b.w;
#pragma unroll
        for (int o = 32; o > 0; o >>= 1) t += __shfl_down(t, o, 64);
        if (lane == 0) bias10[row * 10 + c] = t;
    }
}

// ---------------------------------------------------------------------------
// K2: dist (B,L,Q,16) -> dA (B,L,H,QP), dtB (B,L,H,QP), Cm (B,L,QP)
// ---------------------------------------------------------------------------
__global__ __launch_bounds__(256) void k2_dist(const float* __restrict__ dist,
                                               const float* __restrict__ bias10,
                                               const float* __restrict__ W_bc,
                                               const float* __restrict__ W_dt,
                                               const float* __restrict__ dt_bias,
                                               const float* __restrict__ A_log,
                                               float* __restrict__ dA,
                                               float* __restrict__ dtB,
                                               float* __restrict__ Cm) {
    __shared__ float sWbc[32], sWdt[128], sb[8], sA[8];
    int tid = threadIdx.x;
    if (tid < 32) sWbc[tid] = W_bc[tid];
    else if (tid < 160) sWdt[tid - 32] = W_dt[tid - 32];
    else if (tid < 168) sb[tid - 160] = dt_bias[tid - 160];
    else if (tid < 176) sA[tid - 168] = -expf(A_log[tid - 168]);
    __syncthreads();
    int gid = blockIdx.x * 256 + tid;          // (b*L + l)*Q + q
    if (gid >= BB * LL * QQ) return;
    int q = gid % QQ;
    int bl = gid / QQ;
    const float* dp = dist + (size_t)gid * 16;
    float d[16];
    float4 d0 = *(const float4*)(dp + 0);
    float4 d1 = *(const float4*)(dp + 4);
    float4 d2 = *(const float4*)(dp + 8);
    float4 d3 = *(const float4*)(dp + 12);
    d[0]=d0.x; d[1]=d0.y; d[2]=d0.z; d[3]=d0.w;
    d[4]=d1.x; d[5]=d1.y; d[6]=d1.z; d[7]=d1.w;
    d[8]=d2.x; d[9]=d2.y; d[10]=d2.z; d[11]=d2.w;
    d[12]=d3.x; d[13]=d3.y; d[14]=d3.z; d[15]=d3.w;
    float bc0 = 0.f, bc1 = 0.f;
#pragma unroll
    for (int m = 0; m < 16; m++) {
        bc0 = fmaf(d[m], sWbc[m], bc0);
        bc1 = fmaf(d[m], sWbc[16 + m], bc1);
    }
    float Bmv = bc0 + bias10[bl * 10 + 0];
    float Cv  = bc1 + bias10[bl * 10 + 1];
    Cm[bl * QP + q] = Cv;
#pragma unroll
    for (int h = 0; h < 8; h++) {
        float t = 0.f;
#pragma unroll
        for (int m = 0; m < 16; m++) t = fmaf(d[m], sWdt[h * 16 + m], t);
        float pre = t + bias10[bl * 10 + 2 + h] + sb[h];
        float dt = (pre > 20.f) ? pre : log1pf(expf(pre));
        int o = (bl * 8 + h) * QP + q;
        dA[o]  = expf(sA[h] * dt);
        dtB[o] = dt * Bmv;
    }
}

// ---------------------------------------------------------------------------
// K2b: per-segment decay product  segd (B,NSEG,H,QP)
// ---------------------------------------------------------------------------
__global__ __launch_bounds__(256) void k2b_segdecay(const float* __restrict__ dA,
                                                    float* __restrict__ segd) {
    int gid = blockIdx.x * 256 + threadIdx.x;   // ((b*16+s)*8+h)*QP+q
    if (gid >= BB * NSEG * 8 * QP) return;
    int q = gid % QP; int r = gid / QP;
    int h = r % 8; r /= 8;
    int s = r % NSEG; int b = r / NSEG;
    int base = ((b * LL + s * SEGLEN) * 8 + h) * QP + q;
    float p = 1.f;
    for (int i = 0; i < SEGLEN; i++) p *= dA[base + i * 8 * QP];
    segd[gid] = p;
}

// ---------------------------------------------------------------------------
// Pass A: segment-local state march (S_in = 0), writes S_local.
// grid (NSEG, 32, 2), block 512. lane = pp*8+nn: wave w owns p = w*8+pp,
// lane scans n in [nn*40, nn*40+40). Operands staged in LDS in groups of
// G=4 iterations, double-buffered: [dA 0..319 | dtB 320..639 | x 640..703].
// One barrier per 4 timesteps; no cross-lane work needed.
// ---------------------------------------------------------------------------
__global__ __launch_bounds__(512, 6) void pass_a(const float* __restrict__ dA,
                                                 const float* __restrict__ dtB,
                                                 const float* __restrict__ zx,
                                                 float* __restrict__ S_local) {
    __shared__ __align__(16) float sOp[2][4][704];
    int seg = blockIdx.x, bh = blockIdx.y, dir = blockIdx.z;
    int tid = threadIdx.x;
    int w = tid >> 6, lane = tid & 63;
    int nn = lane & 7, pp = lane >> 3;
    int p = w * 8 + pp;
    int b = bh >> 3, h = bh & 7;
    float S[40];
#pragma unroll
    for (int j = 0; j < 40; j++) S[j] = 0.f;

    auto stage = [&](int g, int buf) {
#pragma unroll
        for (int k = 0; k < 2; k++) {
            int idx = tid + k * 512;
            if (idx < 704) {
                int it = idx / 176;
                int pos = (idx % 176) * 4;
                int i = g * 4 + it;
                int l = dir ? (LL - 1 - (seg * SEGLEN + i)) : (seg * SEGLEN + i);
                int bl = b * LL + l;
                const float* src;
                if (pos < 320)      src = dA  + (size_t)(bl * 8 + h) * QP + pos;
                else if (pos < 640) src = dtB + (size_t)(bl * 8 + h) * QP + (pos - 320);
                else                src = zx + (size_t)bl * 1024 + 512 + h * 64 + (pos - 640);
                *(float4*)&sOp[buf][it][pos] = *(const float4*)src;
            }
        }
    };
    stage(0, 0);
    for (int g = 0; g < SEGLEN / 4; g++) {
        __syncthreads();
        if (g + 1 < SEGLEN / 4) stage(g + 1, (g + 1) & 1);
#pragma unroll
        for (int it = 0; it < 4; it++) {
            const float* bufc = sOp[g & 1][it];
            float x = bufc[640 + p];
#pragma unroll
            for (int c = 0; c < 10; c++) {
                float4 a4 = *(const float4*)(bufc + nn * 40 + c * 4);
                float4 b4 = *(const float4*)(bufc + 320 + nn * 40 + c * 4);
                S[c * 4 + 0] = fmaf(S[c * 4 + 0], a4.x, b4.x * x);
                S[c * 4 + 1] = fmaf(S[c * 4 + 1], a4.y, b4.y * x);
                S[c * 4 + 2] = fmaf(S[c * 4 + 2], a4.z, b4.z * x);
                S[c * 4 + 3] = fmaf(S[c * 4 + 3], a4.w, b4.w * x);
            }
        }
    }
    size_t base = (size_t)((dir * NSEG + seg) * 32 + bh) * QP * 64;
#pragma unroll
    for (int j = 0; j < 40; j++)
        S_local[base + (size_t)(nn * 40 + j) * 64 + p] = S[j];
}

// ---------------------------------------------------------------------------
// Pass B: sequential segment combine (16 steps), writes S_in per segment and
// the averaged final state Savg (B,H,QP,P)
// ---------------------------------------------------------------------------
__global__ __launch_bounds__(256) void pass_b(const float* __restrict__ S_local,
                                              const float* __restrict__ segd,
                                              const float* __restrict__ S0q,
                                              float* __restrict__ S_in,
                                              float* __restrict__ Savg) {
    int gid = blockIdx.x * 256 + threadIdx.x;   // (b,h,n,p)
    if (gid >= BB * 8 * QP * 64) return;
    int p = gid & 63; int r = gid >> 6;
    int n = r % QP; r /= QP;
    int h = r & 7; int b = r >> 3;
    int bh = b * 8 + h;
    float s0 = (n < QQ) ? S0q[(size_t)(b * QQ + n) * 512 + h * 64 + p] : 0.f;
    float Sf = 0.f, Sb = 0.f;
    for (int dir = 0; dir < 2; dir++) {
        float S = s0;
        for (int s = 0; s < NSEG; s++) {
            size_t idx = (size_t)(((dir * NSEG + s) * 32 + bh) * QP + n) * 64 + p;
            S_in[idx] = S;
            int sf = dir ? (NSEG - 1 - s) : s;
            float dec = segd[((b * NSEG + sf) * 8 + h) * QP + n];
            S = fmaf(S, dec, S_local[idx]);
        }
        if (dir == 0) Sf = S; else Sb = S;
    }
    Savg[((bh) * QP + n) * 64 + p] = 0.5f * (Sf + Sb);
}

// ---------------------------------------------------------------------------
// Pass C: replay with true S_in, compute y (without Dp*x), write y_f / y_b.
// Same lane layout as pass_a; y = sum over n = in-lane chain (40) then
// 3x shfl_xor across nn bits. LDS: [dA|dtB|Cm|x] = 1024 floats/iter, G=4
// double-buffered. No ybuf, 1 barrier / 4 timesteps.
// ---------------------------------------------------------------------------
__global__ __launch_bounds__(512, 6) void pass_c(const float* __restrict__ dA,
                                                 const float* __restrict__ dtB,
                                                 const float* __restrict__ Cm,
                                                 const float* __restrict__ zx,
                                                 const float* __restrict__ S_in,
                                                 float* __restrict__ yf,
                                                 float* __restrict__ yb) {
    __shared__ __align__(16) float sOp[2][4][1024];
    int seg = blockIdx.x, bh = blockIdx.y, dir = blockIdx.z;
    int tid = threadIdx.x;
    int w = tid >> 6, lane = tid & 63;
    int nn = lane & 7, pp = lane >> 3;
    int p = w * 8 + pp;
    int b = bh >> 3, h = bh & 7;
    float S[40];
    size_t sbase = (size_t)((dir * NSEG + seg) * 32 + bh) * QP * 64;
#pragma unroll
    for (int j = 0; j < 40; j++) S[j] = S_in[sbase + (size_t)(nn * 40 + j) * 64 + p];
    float* __restrict__ yo = dir ? yb : yf;

    auto stage = [&](int g, int buf) {
#pragma unroll
        for (int k = 0; k < 2; k++) {
            int idx = tid + k * 512;
            int it = idx >> 8;
            int pos = (idx & 255) * 4;
            int i = g * 4 + it;
            int l = dir ? (LL - 1 - (seg * SEGLEN + i)) : (seg * SEGLEN + i);
            int bl = b * LL + l;
            const float* src;
            if (pos < 320)      src = dA  + (size_t)(bl * 8 + h) * QP + pos;
            else if (pos < 640) src = dtB + (size_t)(bl * 8 + h) * QP + (pos - 320);
            else if (pos < 960) src = Cm + (size_t)bl * QP + (pos - 640);
            else                src = zx + (size_t)bl * 1024 + 512 + h * 64 + (pos - 960);
            *(float4*)&sOp[buf][it][pos] = *(const float4*)src;
        }
    };
    stage(0, 0);
    for (int g = 0; g < SEGLEN / 4; g++) {
        __syncthreads();
        if (g + 1 < SEGLEN / 4) stage(g + 1, (g + 1) & 1);
#pragma unroll
        for (int it = 0; it < 4; it++) {
            int i = g * 4 + it;
            int l = dir ? (LL - 1 - (seg * SEGLEN + i)) : (seg * SEGLEN + i);
            int bl = b * LL + l;
            const float* bufc = sOp[g & 1][it];
            float x = bufc[960 + p];
            float y = 0.f;
#pragma unroll
            for (int c = 0; c < 10; c++) {
                float4 a4 = *(const float4*)(bufc + nn * 40 + c * 4);
                float4 b4 = *(const float4*)(bufc + 320 + nn * 40 + c * 4);
                float4 c4 = *(const float4*)(bufc + 640 + nn * 40 + c * 4);
                S[c * 4 + 0] = fmaf(S[c * 4 + 0], a4.x, b4.x * x); y = fmaf(S[c * 4 + 0], c4.x, y);
                S[c * 4 + 1] = fmaf(S[c * 4 + 1], a4.y, b4.y * x); y = fmaf(S[c * 4 + 1], c4.y, y);
                S[c * 4 + 2] = fmaf(S[c * 4 + 2], a4.z, b4.z * x); y = fmaf(S[c * 4 + 2], c4.z, y);
                S[c * 4 + 3] = fmaf(S[c * 4 + 3], a4.w, b4.w * x); y = fmaf(S[c * 4 + 3], c4.w, y);
            }
            y += __shfl_xor(y, 1, 64);
            y += __shfl_xor(y, 2, 64);
            y += __shfl_xor(y, 4, 64);
            if (nn == 0) yo[(size_t)(bl * 8 + h) * 64 + p] = y;
        }
    }
}

// ---------------------------------------------------------------------------
// K4: y = 0.5*(yf+yb) + Dp*x ; g = y*silu(z) ; key = g * rms(g) * key_norm_w
// ---------------------------------------------------------------------------
__global__ __launch_bounds__(512) void k4_gate(const float* __restrict__ yf,
                                               const float* __restrict__ yb,
                                               const float* __restrict__ zx,
                                               const float* __restrict__ Dp,
                                               const float* __restrict__ knw,
                                               float* __restrict__ key) {
    int bl = blockIdx.x;
    int t = threadIdx.x;
    int h = t >> 6;
    float x = zx[(size_t)bl * 1024 + 512 + t];
    float yv = 0.5f * (yf[(size_t)bl * 512 + t] + yb[(size_t)bl * 512 + t]) + Dp[h] * x;
    float z = zx[(size_t)bl * 1024 + t];
    float g = yv * (z / (1.f + expf(-z)));
    float v = g * g;
#pragma unroll
    for (int o = 32; o > 0; o >>= 1) v += __shfl_down(v, o, 64);
    __shared__ float rs[8];
    __shared__ float stot;
    if ((t & 63) == 0) rs[t >> 6] = v;
    __syncthreads();
    if (t == 0) {
        float s = 0.f;
#pragma unroll
        for (int i = 0; i < 8; i++) s += rs[i];
        stot = s;
    }
    __syncthreads();
    float rms = rsqrtf(stot / 512.f + 1e-5f);
    key[(size_t)bl * 512 + t] = g * rms * knw[t];
}

// ---------------------------------------------------------------------------
// K5: layernorm on Savg rearranged to (B,Q,512); one block per (b,q)
// ---------------------------------------------------------------------------
__global__ __launch_bounds__(512) void k5_ln(const float* __restrict__ Savg,
                                             const float* __restrict__ lnw,
                                             const float* __restrict__ lnb,
                                             float* __restrict__ lsn) {
    int bq = blockIdx.x;
    int b = bq / QQ, q = bq % QQ;
    int t = threadIdx.x;
    int h = t >> 6, p = t & 63;
    float v = Savg[((b * 8 + h) * QP + q) * 64 + p];
    float s1 = v, s2 = v * v;
#pragma unroll
    for (int o = 32; o > 0; o >>= 1) {
        s1 += __shfl_down(s1, o, 64);
        s2 += __shfl_down(s2, o, 64);
    }
    __shared__ float r1[8], r2[8];
    __shared__ float smu, srv;
    if ((t & 63) == 0) { r1[t >> 6] = s1; r2[t >> 6] = s2; }
    __syncthreads();
    if (t == 0) {
        float a = 0.f, c = 0.f;
#pragma unroll
        for (int i = 0; i < 8; i++) { a += r1[i]; c += r2[i]; }
        float mu = a / 512.f;
        float var = c / 512.f - mu * mu;
        smu = mu;
        srv = rsqrtf(var + 1e-5f);
    }
    __syncthreads();
    lsn[(size_t)bq * 512 + t] = (v - smu) * srv * lnw[t] + lnb[t];
}

// ---------------------------------------------------------------------------
extern "C" void kernel_launch(void* const* d_in, const int* in_sizes, int n_in,
                              void* d_out, int out_size, void* d_ws, size_t ws_size,
                              hipStream_t stream) {
    const float* in_key    = (const float*)d_in[0];
    const float* in_query  = (const float*)d_in[1];
    const float* dist      = (const float*)d_in[2];
    const float* W_key     = (const float*)d_in[3];
    const float* W_query   = (const float*)d_in[4];
    const float* W_bc      = (const float*)d_in[5];
    const float* W_dt      = (const float*)d_in[6];
    const float* dt_bias   = (const float*)d_in[7];
    const float* A_log     = (const float*)d_in[8];
    const float* Dp        = (const float*)d_in[9];
    const float* W_out_key = (const float*)d_in[10];
    const float* W_out_query = (const float*)d_in[11];
    const float* key_norm_w = (const float*)d_in[12];
    const float* ln_w      = (const float*)d_in[13];
    const float* ln_b      = (const float*)d_in[14];

    float* out_key = (float*)d_out;
    float* out_query = out_key + (size_t)BB * LL * D_MODEL;   // 2,097,152

    char* w8 = (char*)d_ws;
    auto alloc = [&](size_t bytes) {
        char* ptr = w8;
        w8 += (bytes + 255) & ~(size_t)255;
        return ptr;
    };
    float* zx     = (float*)alloc((size_t)8192 * 1024 * 4);
    float* bias10 = (float*)alloc((size_t)8192 * 10 * 4);
    float* S0q    = (float*)alloc((size_t)1200 * 512 * 4);
    float* dAb    = (float*)alloc((size_t)8192 * 8 * QP * 4);
    float* dtBb   = (float*)alloc((size_t)8192 * 8 * QP * 4);
    float* Cmb    = (float*)alloc((size_t)8192 * QP * 4);
    float* segd   = (float*)alloc((size_t)BB * NSEG * 8 * QP * 4);
    float* Sloc   = (float*)alloc((size_t)2 * NSEG * 32 * QP * 64 * 4);
    float* Sin    = (float*)alloc((size_t)2 * NSEG * 32 * QP * 64 * 4);
    float* yfb    = (float*)alloc((size_t)8192 * 512 * 4);
    float* ybb    = (float*)alloc((size_t)8192 * 512 * 4);
    float* Savg   = (float*)alloc((size_t)32 * QP * 64 * 4);
    float* keyb   = (float*)alloc((size_t)8192 * 512 * 4);
    float* lsn    = (float*)alloc((size_t)1200 * 512 * 4);
    ushort_t* ink_h  = (ushort_t*)alloc((size_t)2097152 * 2);
    ushort_t* ink_l  = (ushort_t*)alloc((size_t)2097152 * 2);
    ushort_t* wk_h   = (ushort_t*)alloc((size_t)262144 * 2);
    ushort_t* wk_l   = (ushort_t*)alloc((size_t)262144 * 2);
    ushort_t* inq_h  = (ushort_t*)alloc((size_t)307200 * 2);
    ushort_t* inq_l  = (ushort_t*)alloc((size_t)307200 * 2);
    ushort_t* wq_h   = (ushort_t*)alloc((size_t)131072 * 2);
    ushort_t* wq_l   = (ushort_t*)alloc((size_t)131072 * 2);
    ushort_t* keyb_h = (ushort_t*)alloc((size_t)4194304 * 2);
    ushort_t* keyb_l = (ushort_t*)alloc((size_t)4194304 * 2);
    ushort_t* wok_h  = (ushort_t*)alloc((size_t)131072 * 2);
    ushort_t* wok_l  = (ushort_t*)alloc((size_t)131072 * 2);
    ushort_t* lsn_h  = (ushort_t*)alloc((size_t)614400 * 2);
    ushort_t* lsn_l  = (ushort_t*)alloc((size_t)614400 * 2);
    ushort_t* woq_h  = (ushort_t*)alloc((size_t)131072 * 2);
    ushort_t* woq_l  = (ushort_t*)alloc((size_t)131072 * 2);

    // Input conversions (bf16 hi/lo)
    c_split<<<8192, 256, 0, stream>>>(in_key, ink_h, ink_l, 2097152);
    c_split<<<1024, 256, 0, stream>>>(W_key, wk_h, wk_l, 262144);       // rows 0..1023
    c_split<<<1200, 256, 0, stream>>>(in_query, inq_h, inq_l, 307200);
    c_split<<<512, 256, 0, stream>>>(W_query, wq_h, wq_l, 131072);
    c_split<<<512, 256, 0, stream>>>(W_out_key, wok_h, wok_l, 131072);
    c_split<<<512, 256, 0, stream>>>(W_out_query, woq_h, woq_l, 131072);

    // Projections
    gemm_bf16s<<<dim3(16, 64), 256, 0, stream>>>(ink_h, ink_l, wk_h, wk_l, zx, 8192, 1024, 256);
    k1b_bias<<<2048, 256, 0, stream>>>(in_key, W_key, bias10);
    gemm_bf16s<<<dim3(8, 10), 256, 0, stream>>>(inq_h, inq_l, wq_h, wq_l, S0q, 1200, 512, 256);

    // dist -> dA, dtB, Cm
    k2_dist<<<9600, 256, 0, stream>>>(dist, bias10, W_bc, W_dt, dt_bias, A_log, dAb, dtBb, Cmb);
    k2b_segdecay<<<640, 256, 0, stream>>>(dAb, segd);

    // 3-pass segmented bidirectional scan
    pass_a<<<dim3(NSEG, 32, 2), 512, 0, stream>>>(dAb, dtBb, zx, Sloc);
    pass_b<<<2560, 256, 0, stream>>>(Sloc, segd, S0q, Sin, Savg);
    pass_c<<<dim3(NSEG, 32, 2), 512, 0, stream>>>(dAb, dtBb, Cmb, zx, Sin, yfb, ybb);

    // out_key path
    k4_gate<<<8192, 512, 0, stream>>>(yfb, ybb, zx, Dp, key_norm_w, keyb);
    c_split<<<16384, 256, 0, stream>>>(keyb, keyb_h, keyb_l, 4194304);
    gemm_bf16s<<<dim3(4, 64), 256, 0, stream>>>(keyb_h, keyb_l, wok_h, wok_l, out_key, 8192, 256, 512);

    // out_query path
    k5_ln<<<1200, 512, 0, stream>>>(Savg, ln_w, ln_b, lsn);
    c_split<<<2400, 256, 0, stream>>>(lsn, lsn_h, lsn_l, 614400);
    gemm_bf16s<<<dim3(4, 10), 256, 0, stream>>>(lsn_h, lsn_l, woq_h, woq_l, out_query, 1200, 256, 512);
}

// Round 4
// 1076.493 us; speedup vs baseline: 1.1478x; 1.1478x over previous
//
#include <hip/hip_runtime.h>
#include <hip/hip_bf16.h>

// Problem constants
#define D_MODEL 256
#define D_INNER 512
#define NHEADS 8
#define HEADDIM 64
#define MDIST 16
#define BB 4
#define LL 2048
#define QQ 300
#define QP 320          // padded Q (5*64; each lane scans 40 n's)
#define NSEG 16
#define SEGLEN 128      // LL / NSEG

typedef unsigned short ushort_t;
typedef __attribute__((ext_vector_type(8))) short bf16x8;
typedef __attribute__((ext_vector_type(4))) float f32x4;

// ---------------------------------------------------------------------------
// Split fp32 -> bf16 hi + bf16 lo (residual). C = Ah*Bh + Ah*Bl + Al*Bh gives
// ~fp32 accuracy (missing Al*Bl term ~2^-18 relative).
// ---------------------------------------------------------------------------
__global__ __launch_bounds__(256) void c_split(const float* __restrict__ in,
                                               ushort_t* __restrict__ hi,
                                               ushort_t* __restrict__ lo, int n) {
    int i = blockIdx.x * 256 + threadIdx.x;
    if (i >= n) return;
    float v = in[i];
    __hip_bfloat16 h = __float2bfloat16(v);
    float hf = __bfloat162float(h);
    __hip_bfloat16 l = __float2bfloat16(v - hf);
    hi[i] = *(ushort_t*)&h;
    lo[i] = *(ushort_t*)&l;
}

// ---------------------------------------------------------------------------
// Split-bf16 MFMA GEMM: C[M,N] = A[M,K] * B[N,K]^T (NT), fp32 out.
// K mult of 32, N mult of 64. Block 256 = 4 waves; block tile 128m x 64n;
// wave tile 32m x 64n. No LDS: frags load 16B contiguous-in-K from global
// (weights L1/L2 resident). mfma_f32_16x16x32_bf16 layout (m89-verified):
//   A[m=lane&15][k=(lane>>4)*8+j]; B[k=(lane>>4)*8+j][n=lane&15];
//   D[row=(lane>>4)*4+r][col=lane&15].
// ---------------------------------------------------------------------------
__global__ __launch_bounds__(256) void gemm_bf16s(const ushort_t* __restrict__ Ah,
                                                  const ushort_t* __restrict__ Al,
                                                  const ushort_t* __restrict__ Bh,
                                                  const ushort_t* __restrict__ Bl,
                                                  float* __restrict__ C,
                                                  int M, int N, int K) {
    int w = threadIdx.x >> 6, lane = threadIdx.x & 63;
    int n0 = blockIdx.x * 64;
    int m0 = blockIdx.y * 128 + w * 32;
    int lm = lane & 15, lk = (lane >> 4) * 8;
    f32x4 acc[2][4];
#pragma unroll
    for (int i = 0; i < 2; i++)
#pragma unroll
        for (int j = 0; j < 4; j++) acc[i][j] = {0.f, 0.f, 0.f, 0.f};

    for (int k0 = 0; k0 < K; k0 += 32) {
        bf16x8 ah[2], al[2], bh[4], blo[4];
#pragma unroll
        for (int mf = 0; mf < 2; mf++) {
            int row = m0 + mf * 16 + lm;
            if (row >= M) row = M - 1;            // safe clamp; epilogue guards
            size_t off = (size_t)row * K + k0 + lk;
            ah[mf] = *(const bf16x8*)(Ah + off);
            al[mf] = *(const bf16x8*)(Al + off);
        }
#pragma unroll
        for (int nf = 0; nf < 4; nf++) {
            int col = n0 + nf * 16 + lm;
            size_t off = (size_t)col * K + k0 + lk;
            bh[nf]  = *(const bf16x8*)(Bh + off);
            blo[nf] = *(const bf16x8*)(Bl + off);
        }
#pragma unroll
        for (int mf = 0; mf < 2; mf++)
#pragma unroll
            for (int nf = 0; nf < 4; nf++) {
                acc[mf][nf] = __builtin_amdgcn_mfma_f32_16x16x32_bf16(ah[mf], bh[nf],  acc[mf][nf], 0, 0, 0);
                acc[mf][nf] = __builtin_amdgcn_mfma_f32_16x16x32_bf16(ah[mf], blo[nf], acc[mf][nf], 0, 0, 0);
                acc[mf][nf] = __builtin_amdgcn_mfma_f32_16x16x32_bf16(al[mf], bh[nf],  acc[mf][nf], 0, 0, 0);
            }
    }
#pragma unroll
    for (int mf = 0; mf < 2; mf++)
#pragma unroll
        for (int nf = 0; nf < 4; nf++)
#pragma unroll
            for (int r = 0; r < 4; r++) {
                int m = m0 + mf * 16 + (lane >> 4) * 4 + r;
                if (m < M) C[(size_t)m * N + n0 + nf * 16 + lm] = acc[mf][nf][r];
            }
}

// ---------------------------------------------------------------------------
// K1b: fp32 bias columns (rows 1024..1033 of W_key) — precision-critical
// (feeds exp(A*dt)). bias10[bl][c] = in_key[bl] . W_key[1024+c]
// ---------------------------------------------------------------------------
__global__ __launch_bounds__(256) void k1b_bias(const float* __restrict__ in_key,
                                                const float* __restrict__ W_key,
                                                float* __restrict__ bias10) {
    int w = threadIdx.x >> 6, lane = threadIdx.x & 63;
    int row = blockIdx.x * 4 + w;
    float4 a = *(const float4*)(in_key + (size_t)row * 256 + lane * 4);
#pragma unroll
    for (int c = 0; c < 10; c++) {
        float4 b = *(const float4*)(W_key + (size_t)(1024 + c) * 256 + lane * 4);
        float t = a.x * b.x + a.y * b.y + a.z * b.z + a.w * b.w;
#pragma unroll
        for (int o = 32; o > 0; o >>= 1) t += __shfl_down(t, o, 64);
        if (lane == 0) bias10[row * 10 + c] = t;
    }
}

// ---------------------------------------------------------------------------
// K2: dist (B,L,Q,16) -> dA (B,L,H,QP), dtB (B,L,H,QP), Cm (B,L,QP)
// ---------------------------------------------------------------------------
__global__ __launch_bounds__(256) void k2_dist(const float* __restrict__ dist,
                                               const float* __restrict__ bias10,
                                               const float* __restrict__ W_bc,
                                               const float* __restrict__ W_dt,
                                               const float* __restrict__ dt_bias,
                                               const float* __restrict__ A_log,
                                               float* __restrict__ dA,
                                               float* __restrict__ dtB,
                                               float* __restrict__ Cm) {
    __shared__ float sWbc[32], sWdt[128], sb[8], sA[8];
    int tid = threadIdx.x;
    if (tid < 32) sWbc[tid] = W_bc[tid];
    else if (tid < 160) sWdt[tid - 32] = W_dt[tid - 32];
    else if (tid < 168) sb[tid - 160] = dt_bias[tid - 160];
    else if (tid < 176) sA[tid - 168] = -expf(A_log[tid - 168]);
    __syncthreads();
    int gid = blockIdx.x * 256 + tid;          // (b*L + l)*Q + q
    if (gid >= BB * LL * QQ) return;
    int q = gid % QQ;
    int bl = gid / QQ;
    const float* dp = dist + (size_t)gid * 16;
    float d[16];
    float4 d0 = *(const float4*)(dp + 0);
    float4 d1 = *(const float4*)(dp + 4);
    float4 d2 = *(const float4*)(dp + 8);
    float4 d3 = *(const float4*)(dp + 12);
    d[0]=d0.x; d[1]=d0.y; d[2]=d0.z; d[3]=d0.w;
    d[4]=d1.x; d[5]=d1.y; d[6]=d1.z; d[7]=d1.w;
    d[8]=d2.x; d[9]=d2.y; d[10]=d2.z; d[11]=d2.w;
    d[12]=d3.x; d[13]=d3.y; d[14]=d3.z; d[15]=d3.w;
    float bc0 = 0.f, bc1 = 0.f;
#pragma unroll
    for (int m = 0; m < 16; m++) {
        bc0 = fmaf(d[m], sWbc[m], bc0);
        bc1 = fmaf(d[m], sWbc[16 + m], bc1);
    }
    float Bmv = bc0 + bias10[bl * 10 + 0];
    float Cv  = bc1 + bias10[bl * 10 + 1];
    Cm[bl * QP + q] = Cv;
#pragma unroll
    for (int h = 0; h < 8; h++) {
        float t = 0.f;
#pragma unroll
        for (int m = 0; m < 16; m++) t = fmaf(d[m], sWdt[h * 16 + m], t);
        float pre = t + bias10[bl * 10 + 2 + h] + sb[h];
        float dt = (pre > 20.f) ? pre : log1pf(expf(pre));
        int o = (bl * 8 + h) * QP + q;
        dA[o]  = expf(sA[h] * dt);
        dtB[o] = dt * Bmv;
    }
}

// ---------------------------------------------------------------------------
// K2b: per-segment decay product  segd (B,NSEG,H,QP)
// ---------------------------------------------------------------------------
__global__ __launch_bounds__(256) void k2b_segdecay(const float* __restrict__ dA,
                                                    float* __restrict__ segd) {
    int gid = blockIdx.x * 256 + threadIdx.x;   // ((b*16+s)*8+h)*QP+q
    if (gid >= BB * NSEG * 8 * QP) return;
    int q = gid % QP; int r = gid / QP;
    int h = r % 8; r /= 8;
    int s = r % NSEG; int b = r / NSEG;
    int base = ((b * LL + s * SEGLEN) * 8 + h) * QP + q;
    float p = 1.f;
    for (int i = 0; i < SEGLEN; i++) p *= dA[base + i * 8 * QP];
    segd[gid] = p;
}

// ---------------------------------------------------------------------------
// Pass A: segment-local state march (S_in = 0), writes S_local.
// grid (NSEG, 32, 2), block 512. lane = pp*8+nn: wave w owns p = w*8+pp,
// lane scans n in [nn*40, nn*40+40). Operands staged in LDS in groups of
// G=4 iterations, double-buffered: [dA 0..319 | dtB 320..639 | x 640..703].
// One barrier per 4 timesteps; no cross-lane work needed.
// NOTE: plain __launch_bounds__(512) — a min-waves/EU hint of 6 in R3 capped
// the allocator and spilled S[40] to scratch (VGPR 56->40, +76MB fetch).
// ---------------------------------------------------------------------------
__global__ __launch_bounds__(512) void pass_a(const float* __restrict__ dA,
                                              const float* __restrict__ dtB,
                                              const float* __restrict__ zx,
                                              float* __restrict__ S_local) {
    __shared__ __align__(16) float sOp[2][4][704];
    int seg = blockIdx.x, bh = blockIdx.y, dir = blockIdx.z;
    int tid = threadIdx.x;
    int w = tid >> 6, lane = tid & 63;
    int nn = lane & 7, pp = lane >> 3;
    int p = w * 8 + pp;
    int b = bh >> 3, h = bh & 7;
    float S[40];
#pragma unroll
    for (int j = 0; j < 40; j++) S[j] = 0.f;

    auto stage = [&](int g, int buf) {
#pragma unroll
        for (int k = 0; k < 2; k++) {
            int idx = tid + k * 512;
            if (idx < 704) {
                int it = idx / 176;
                int pos = (idx % 176) * 4;
                int i = g * 4 + it;
                int l = dir ? (LL - 1 - (seg * SEGLEN + i)) : (seg * SEGLEN + i);
                int bl = b * LL + l;
                const float* src;
                if (pos < 320)      src = dA  + (size_t)(bl * 8 + h) * QP + pos;
                else if (pos < 640) src = dtB + (size_t)(bl * 8 + h) * QP + (pos - 320);
                else                src = zx + (size_t)bl * 1024 + 512 + h * 64 + (pos - 640);
                *(float4*)&sOp[buf][it][pos] = *(const float4*)src;
            }
        }
    };
    stage(0, 0);
    for (int g = 0; g < SEGLEN / 4; g++) {
        __syncthreads();
        if (g + 1 < SEGLEN / 4) stage(g + 1, (g + 1) & 1);
#pragma unroll
        for (int it = 0; it < 4; it++) {
            const float* bufc = sOp[g & 1][it];
            float x = bufc[640 + p];
#pragma unroll
            for (int c = 0; c < 10; c++) {
                float4 a4 = *(const float4*)(bufc + nn * 40 + c * 4);
                float4 b4 = *(const float4*)(bufc + 320 + nn * 40 + c * 4);
                S[c * 4 + 0] = fmaf(S[c * 4 + 0], a4.x, b4.x * x);
                S[c * 4 + 1] = fmaf(S[c * 4 + 1], a4.y, b4.y * x);
                S[c * 4 + 2] = fmaf(S[c * 4 + 2], a4.z, b4.z * x);
                S[c * 4 + 3] = fmaf(S[c * 4 + 3], a4.w, b4.w * x);
            }
        }
    }
    size_t base = (size_t)((dir * NSEG + seg) * 32 + bh) * QP * 64;
#pragma unroll
    for (int j = 0; j < 40; j++)
        S_local[base + (size_t)(nn * 40 + j) * 64 + p] = S[j];
}

// ---------------------------------------------------------------------------
// Pass B: sequential segment combine (16 steps), writes S_in per segment and
// the averaged final state Savg (B,H,QP,P)
// ---------------------------------------------------------------------------
__global__ __launch_bounds__(256) void pass_b(const float* __restrict__ S_local,
                                              const float* __restrict__ segd,
                                              const float* __restrict__ S0q,
                                              float* __restrict__ S_in,
                                              float* __restrict__ Savg) {
    int gid = blockIdx.x * 256 + threadIdx.x;   // (b,h,n,p)
    if (gid >= BB * 8 * QP * 64) return;
    int p = gid & 63; int r = gid >> 6;
    int n = r % QP; r /= QP;
    int h = r & 7; int b = r >> 3;
    int bh = b * 8 + h;
    float s0 = (n < QQ) ? S0q[(size_t)(b * QQ + n) * 512 + h * 64 + p] : 0.f;
    float Sf = 0.f, Sb = 0.f;
    for (int dir = 0; dir < 2; dir++) {
        float S = s0;
        for (int s = 0; s < NSEG; s++) {
            size_t idx = (size_t)(((dir * NSEG + s) * 32 + bh) * QP + n) * 64 + p;
            S_in[idx] = S;
            int sf = dir ? (NSEG - 1 - s) : s;
            float dec = segd[((b * NSEG + sf) * 8 + h) * QP + n];
            S = fmaf(S, dec, S_local[idx]);
        }
        if (dir == 0) Sf = S; else Sb = S;
    }
    Savg[((bh) * QP + n) * 64 + p] = 0.5f * (Sf + Sb);
}

// ---------------------------------------------------------------------------
// Pass C: replay with true S_in, compute y (without Dp*x), write y_f / y_b.
// Same lane layout as pass_a; y = sum over n = in-lane chain (40) then
// 3x shfl_xor across nn bits. LDS: [dA|dtB|Cm|x] = 1024 floats/iter, G=4
// double-buffered. No ybuf, 1 barrier / 4 timesteps.
// ---------------------------------------------------------------------------
__global__ __launch_bounds__(512) void pass_c(const float* __restrict__ dA,
                                              const float* __restrict__ dtB,
                                              const float* __restrict__ Cm,
                                              const float* __restrict__ zx,
                                              const float* __restrict__ S_in,
                                              float* __restrict__ yf,
                                              float* __restrict__ yb) {
    __shared__ __align__(16) float sOp[2][4][1024];
    int seg = blockIdx.x, bh = blockIdx.y, dir = blockIdx.z;
    int tid = threadIdx.x;
    int w = tid >> 6, lane = tid & 63;
    int nn = lane & 7, pp = lane >> 3;
    int p = w * 8 + pp;
    int b = bh >> 3, h = bh & 7;
    float S[40];
    size_t sbase = (size_t)((dir * NSEG + seg) * 32 + bh) * QP * 64;
#pragma unroll
    for (int j = 0; j < 40; j++) S[j] = S_in[sbase + (size_t)(nn * 40 + j) * 64 + p];
    float* __restrict__ yo = dir ? yb : yf;

    auto stage = [&](int g, int buf) {
#pragma unroll
        for (int k = 0; k < 2; k++) {
            int idx = tid + k * 512;
            int it = idx >> 8;
            int pos = (idx & 255) * 4;
            int i = g * 4 + it;
            int l = dir ? (LL - 1 - (seg * SEGLEN + i)) : (seg * SEGLEN + i);
            int bl = b * LL + l;
            const float* src;
            if (pos < 320)      src = dA  + (size_t)(bl * 8 + h) * QP + pos;
            else if (pos < 640) src = dtB + (size_t)(bl * 8 + h) * QP + (pos - 320);
            else if (pos < 960) src = Cm + (size_t)bl * QP + (pos - 640);
            else                src = zx + (size_t)bl * 1024 + 512 + h * 64 + (pos - 960);
            *(float4*)&sOp[buf][it][pos] = *(const float4*)src;
        }
    };
    stage(0, 0);
    for (int g = 0; g < SEGLEN / 4; g++) {
        __syncthreads();
        if (g + 1 < SEGLEN / 4) stage(g + 1, (g + 1) & 1);
#pragma unroll
        for (int it = 0; it < 4; it++) {
            int i = g * 4 + it;
            int l = dir ? (LL - 1 - (seg * SEGLEN + i)) : (seg * SEGLEN + i);
            int bl = b * LL + l;
            const float* bufc = sOp[g & 1][it];
            float x = bufc[960 + p];
            float y = 0.f;
#pragma unroll
            for (int c = 0; c < 10; c++) {
                float4 a4 = *(const float4*)(bufc + nn * 40 + c * 4);
                float4 b4 = *(const float4*)(bufc + 320 + nn * 40 + c * 4);
                float4 c4 = *(const float4*)(bufc + 640 + nn * 40 + c * 4);
                S[c * 4 + 0] = fmaf(S[c * 4 + 0], a4.x, b4.x * x); y = fmaf(S[c * 4 + 0], c4.x, y);
                S[c * 4 + 1] = fmaf(S[c * 4 + 1], a4.y, b4.y * x); y = fmaf(S[c * 4 + 1], c4.y, y);
                S[c * 4 + 2] = fmaf(S[c * 4 + 2], a4.z, b4.z * x); y = fmaf(S[c * 4 + 2], c4.z, y);
                S[c * 4 + 3] = fmaf(S[c * 4 + 3], a4.w, b4.w * x); y = fmaf(S[c * 4 + 3], c4.w, y);
            }
            y += __shfl_xor(y, 1, 64);
            y += __shfl_xor(y, 2, 64);
            y += __shfl_xor(y, 4, 64);
            if (nn == 0) yo[(size_t)(bl * 8 + h) * 64 + p] = y;
        }
    }
}

// ---------------------------------------------------------------------------
// K4: y = 0.5*(yf+yb) + Dp*x ; g = y*silu(z) ; key = g * rms(g) * key_norm_w
// ---------------------------------------------------------------------------
__global__ __launch_bounds__(512) void k4_gate(const float* __restrict__ yf,
                                               const float* __restrict__ yb,
                                               const float* __restrict__ zx,
                                               const float* __restrict__ Dp,
                                               const float* __restrict__ knw,
                                               float* __restrict__ key) {
    int bl = blockIdx.x;
    int t = threadIdx.x;
    int h = t >> 6;
    float x = zx[(size_t)bl * 1024 + 512 + t];
    float yv = 0.5f * (yf[(size_t)bl * 512 + t] + yb[(size_t)bl * 512 + t]) + Dp[h] * x;
    float z = zx[(size_t)bl * 1024 + t];
    float g = yv * (z / (1.f + expf(-z)));
    float v = g * g;
#pragma unroll
    for (int o = 32; o > 0; o >>= 1) v += __shfl_down(v, o, 64);
    __shared__ float rs[8];
    __shared__ float stot;
    if ((t & 63) == 0) rs[t >> 6] = v;
    __syncthreads();
    if (t == 0) {
        float s = 0.f;
#pragma unroll
        for (int i = 0; i < 8; i++) s += rs[i];
        stot = s;
    }
    __syncthreads();
    float rms = rsqrtf(stot / 512.f + 1e-5f);
    key[(size_t)bl * 512 + t] = g * rms * knw[t];
}

// ---------------------------------------------------------------------------
// K5: layernorm on Savg rearranged to (B,Q,512); one block per (b,q)
// ---------------------------------------------------------------------------
__global__ __launch_bounds__(512) void k5_ln(const float* __restrict__ Savg,
                                             const float* __restrict__ lnw,
                                             const float* __restrict__ lnb,
                                             float* __restrict__ lsn) {
    int bq = blockIdx.x;
    int b = bq / QQ, q = bq % QQ;
    int t = threadIdx.x;
    int h = t >> 6, p = t & 63;
    float v = Savg[((b * 8 + h) * QP + q) * 64 + p];
    float s1 = v, s2 = v * v;
#pragma unroll
    for (int o = 32; o > 0; o >>= 1) {
        s1 += __shfl_down(s1, o, 64);
        s2 += __shfl_down(s2, o, 64);
    }
    __shared__ float r1[8], r2[8];
    __shared__ float smu, srv;
    if ((t & 63) == 0) { r1[t >> 6] = s1; r2[t >> 6] = s2; }
    __syncthreads();
    if (t == 0) {
        float a = 0.f, c = 0.f;
#pragma unroll
        for (int i = 0; i < 8; i++) { a += r1[i]; c += r2[i]; }
        float mu = a / 512.f;
        float var = c / 512.f - mu * mu;
        smu = mu;
        srv = rsqrtf(var + 1e-5f);
    }
    __syncthreads();
    lsn[(size_t)bq * 512 + t] = (v - smu) * srv * lnw[t] + lnb[t];
}

// ---------------------------------------------------------------------------
extern "C" void kernel_launch(void* const* d_in, const int* in_sizes, int n_in,
                              void* d_out, int out_size, void* d_ws, size_t ws_size,
                              hipStream_t stream) {
    const float* in_key    = (const float*)d_in[0];
    const float* in_query  = (const float*)d_in[1];
    const float* dist      = (const float*)d_in[2];
    const float* W_key     = (const float*)d_in[3];
    const float* W_query   = (const float*)d_in[4];
    const float* W_bc      = (const float*)d_in[5];
    const float* W_dt      = (const float*)d_in[6];
    const float* dt_bias   = (const float*)d_in[7];
    const float* A_log     = (const float*)d_in[8];
    const float* Dp        = (const float*)d_in[9];
    const float* W_out_key = (const float*)d_in[10];
    const float* W_out_query = (const float*)d_in[11];
    const float* key_norm_w = (const float*)d_in[12];
    const float* ln_w      = (const float*)d_in[13];
    const float* ln_b      = (const float*)d_in[14];

    float* out_key = (float*)d_out;
    float* out_query = out_key + (size_t)BB * LL * D_MODEL;   // 2,097,152

    char* w8 = (char*)d_ws;
    auto alloc = [&](size_t bytes) {
        char* ptr = w8;
        w8 += (bytes + 255) & ~(size_t)255;
        return ptr;
    };
    float* zx     = (float*)alloc((size_t)8192 * 1024 * 4);
    float* bias10 = (float*)alloc((size_t)8192 * 10 * 4);
    float* S0q    = (float*)alloc((size_t)1200 * 512 * 4);
    float* dAb    = (float*)alloc((size_t)8192 * 8 * QP * 4);
    float* dtBb   = (float*)alloc((size_t)8192 * 8 * QP * 4);
    float* Cmb    = (float*)alloc((size_t)8192 * QP * 4);
    float* segd   = (float*)alloc((size_t)BB * NSEG * 8 * QP * 4);
    float* Sloc   = (float*)alloc((size_t)2 * NSEG * 32 * QP * 64 * 4);
    float* Sin    = (float*)alloc((size_t)2 * NSEG * 32 * QP * 64 * 4);
    float* yfb    = (float*)alloc((size_t)8192 * 512 * 4);
    float* ybb    = (float*)alloc((size_t)8192 * 512 * 4);
    float* Savg   = (float*)alloc((size_t)32 * QP * 64 * 4);
    float* keyb   = (float*)alloc((size_t)8192 * 512 * 4);
    float* lsn    = (float*)alloc((size_t)1200 * 512 * 4);
    ushort_t* ink_h  = (ushort_t*)alloc((size_t)2097152 * 2);
    ushort_t* ink_l  = (ushort_t*)alloc((size_t)2097152 * 2);
    ushort_t* wk_h   = (ushort_t*)alloc((size_t)262144 * 2);
    ushort_t* wk_l   = (ushort_t*)alloc((size_t)262144 * 2);
    ushort_t* inq_h  = (ushort_t*)alloc((size_t)307200 * 2);
    ushort_t* inq_l  = (ushort_t*)alloc((size_t)307200 * 2);
    ushort_t* wq_h   = (ushort_t*)alloc((size_t)131072 * 2);
    ushort_t* wq_l   = (ushort_t*)alloc((size_t)131072 * 2);
    ushort_t* keyb_h = (ushort_t*)alloc((size_t)4194304 * 2);
    ushort_t* keyb_l = (ushort_t*)alloc((size_t)4194304 * 2);
    ushort_t* wok_h  = (ushort_t*)alloc((size_t)131072 * 2);
    ushort_t* wok_l  = (ushort_t*)alloc((size_t)131072 * 2);
    ushort_t* lsn_h  = (ushort_t*)alloc((size_t)614400 * 2);
    ushort_t* lsn_l  = (ushort_t*)alloc((size_t)614400 * 2);
    ushort_t* woq_h  = (ushort_t*)alloc((size_t)131072 * 2);
    ushort_t* woq_l  = (ushort_t*)alloc((size_t)131072 * 2);

    // Input conversions (bf16 hi/lo)
    c_split<<<8192, 256, 0, stream>>>(in_key, ink_h, ink_l, 2097152);
    c_split<<<1024, 256, 0, stream>>>(W_key, wk_h, wk_l, 262144);       // rows 0..1023
    c_split<<<1200, 256, 0, stream>>>(in_query, inq_h, inq_l, 307200);
    c_split<<<512, 256, 0, stream>>>(W_query, wq_h, wq_l, 131072);
    c_split<<<512, 256, 0, stream>>>(W_out_key, wok_h, wok_l, 131072);
    c_split<<<512, 256, 0, stream>>>(W_out_query, woq_h, woq_l, 131072);

    // Projections
    gemm_bf16s<<<dim3(16, 64), 256, 0, stream>>>(ink_h, ink_l, wk_h, wk_l, zx, 8192, 1024, 256);
    k1b_bias<<<2048, 256, 0, stream>>>(in_key, W_key, bias10);
    gemm_bf16s<<<dim3(8, 10), 256, 0, stream>>>(inq_h, inq_l, wq_h, wq_l, S0q, 1200, 512, 256);

    // dist -> dA, dtB, Cm
    k2_dist<<<9600, 256, 0, stream>>>(dist, bias10, W_bc, W_dt, dt_bias, A_log, dAb, dtBb, Cmb);
    k2b_segdecay<<<640, 256, 0, stream>>>(dAb, segd);

    // 3-pass segmented bidirectional scan
    pass_a<<<dim3(NSEG, 32, 2), 512, 0, stream>>>(dAb, dtBb, zx, Sloc);
    pass_b<<<2560, 256, 0, stream>>>(Sloc, segd, S0q, Sin, Savg);
    pass_c<<<dim3(NSEG, 32, 2), 512, 0, stream>>>(dAb, dtBb, Cmb, zx, Sin, yfb, ybb);

    // out_key path
    k4_gate<<<8192, 512, 0, stream>>>(yfb, ybb, zx, Dp, key_norm_w, keyb);
    c_split<<<16384, 256, 0, stream>>>(keyb, keyb_h, keyb_l, 4194304);
    gemm_bf16s<<<dim3(4, 64), 256, 0, stream>>>(keyb_h, keyb_l, wok_h, wok_l, out_key, 8192, 256, 512);

    // out_query path
    k5_ln<<<1200, 512, 0, stream>>>(Savg, ln_w, ln_b, lsn);
    c_split<<<2400, 256, 0, stream>>>(lsn, lsn_h, lsn_l, 614400);
    gemm_bf16s<<<dim3(4, 10), 256, 0, stream>>>(lsn_h, lsn_l, woq_h, woq_l, out_query, 1200, 256, 512);
}

// Round 5
// 896.269 us; speedup vs baseline: 1.3786x; 1.2011x over previous
//
#include <hip/hip_runtime.h>
#include <hip/hip_bf16.h>

// Problem constants
#define D_MODEL 256
#define D_INNER 512
#define NHEADS 8
#define HEADDIM 64
#define MDIST 16
#define BB 4
#define LL 2048
#define QQ 300
#define QP 320          // padded Q; wave w of 8 owns n-slice [w*40, w*40+40)
#define NSEG 16
#define SEGLEN 128      // LL / NSEG

typedef unsigned short ushort_t;
typedef __attribute__((ext_vector_type(8))) short bf16x8;
typedef __attribute__((ext_vector_type(4))) float f32x4;

__device__ __forceinline__ void bf16_split(float v, ushort_t& hi, ushort_t& lo) {
    __hip_bfloat16 h = __float2bfloat16(v);
    float hf = __bfloat162float(h);
    __hip_bfloat16 l = __float2bfloat16(v - hf);
    hi = *(ushort_t*)&h;
    lo = *(ushort_t*)&l;
}

// ---------------------------------------------------------------------------
// Split fp32 -> bf16 hi + bf16 lo (residual). C = Ah*Bh + Ah*Bl + Al*Bh gives
// ~fp32 accuracy (missing Al*Bl term ~2^-18 relative).
// ---------------------------------------------------------------------------
__global__ __launch_bounds__(256) void c_split(const float* __restrict__ in,
                                               ushort_t* __restrict__ hi,
                                               ushort_t* __restrict__ lo, int n) {
    int i = blockIdx.x * 256 + threadIdx.x;
    if (i >= n) return;
    ushort_t h, l;
    bf16_split(in[i], h, l);
    hi[i] = h;
    lo[i] = l;
}

// ---------------------------------------------------------------------------
// Split-bf16 MFMA GEMM: C[M,N] = A[M,K] * B[N,K]^T (NT), fp32 out.
// mfma_f32_16x16x32_bf16 layout (m89-verified):
//   A[m=lane&15][k=(lane>>4)*8+j]; B[k=(lane>>4)*8+j][n=lane&15];
//   D[row=(lane>>4)*4+r][col=lane&15].
// ---------------------------------------------------------------------------
__global__ __launch_bounds__(256) void gemm_bf16s(const ushort_t* __restrict__ Ah,
                                                  const ushort_t* __restrict__ Al,
                                                  const ushort_t* __restrict__ Bh,
                                                  const ushort_t* __restrict__ Bl,
                                                  float* __restrict__ C,
                                                  int M, int N, int K) {
    int w = threadIdx.x >> 6, lane = threadIdx.x & 63;
    int n0 = blockIdx.x * 64;
    int m0 = blockIdx.y * 128 + w * 32;
    int lm = lane & 15, lk = (lane >> 4) * 8;
    f32x4 acc[2][4];
#pragma unroll
    for (int i = 0; i < 2; i++)
#pragma unroll
        for (int j = 0; j < 4; j++) acc[i][j] = {0.f, 0.f, 0.f, 0.f};

    for (int k0 = 0; k0 < K; k0 += 32) {
        bf16x8 ah[2], al[2], bh[4], blo[4];
#pragma unroll
        for (int mf = 0; mf < 2; mf++) {
            int row = m0 + mf * 16 + lm;
            if (row >= M) row = M - 1;            // safe clamp; epilogue guards
            size_t off = (size_t)row * K + k0 + lk;
            ah[mf] = *(const bf16x8*)(Ah + off);
            al[mf] = *(const bf16x8*)(Al + off);
        }
#pragma unroll
        for (int nf = 0; nf < 4; nf++) {
            int col = n0 + nf * 16 + lm;
            size_t off = (size_t)col * K + k0 + lk;
            bh[nf]  = *(const bf16x8*)(Bh + off);
            blo[nf] = *(const bf16x8*)(Bl + off);
        }
#pragma unroll
        for (int mf = 0; mf < 2; mf++)
#pragma unroll
            for (int nf = 0; nf < 4; nf++) {
                acc[mf][nf] = __builtin_amdgcn_mfma_f32_16x16x32_bf16(ah[mf], bh[nf],  acc[mf][nf], 0, 0, 0);
                acc[mf][nf] = __builtin_amdgcn_mfma_f32_16x16x32_bf16(ah[mf], blo[nf], acc[mf][nf], 0, 0, 0);
                acc[mf][nf] = __builtin_amdgcn_mfma_f32_16x16x32_bf16(al[mf], bh[nf],  acc[mf][nf], 0, 0, 0);
            }
    }
#pragma unroll
    for (int mf = 0; mf < 2; mf++)
#pragma unroll
        for (int nf = 0; nf < 4; nf++)
#pragma unroll
            for (int r = 0; r < 4; r++) {
                int m = m0 + mf * 16 + (lane >> 4) * 4 + r;
                if (m < M) C[(size_t)m * N + n0 + nf * 16 + lm] = acc[mf][nf][r];
            }
}

// ---------------------------------------------------------------------------
// K1b: fp32 bias columns (rows 1024..1033 of W_key) — precision-critical.
// ---------------------------------------------------------------------------
__global__ __launch_bounds__(256) void k1b_bias(const float* __restrict__ in_key,
                                                const float* __restrict__ W_key,
                                                float* __restrict__ bias10) {
    int w = threadIdx.x >> 6, lane = threadIdx.x & 63;
    int row = blockIdx.x * 4 + w;
    float4 a = *(const float4*)(in_key + (size_t)row * 256 + lane * 4);
#pragma unroll
    for (int c = 0; c < 10; c++) {
        float4 b = *(const float4*)(W_key + (size_t)(1024 + c) * 256 + lane * 4);
        float t = a.x * b.x + a.y * b.y + a.z * b.z + a.w * b.w;
#pragma unroll
        for (int o = 32; o > 0; o >>= 1) t += __shfl_down(t, o, 64);
        if (lane == 0) bias10[row * 10 + c] = t;
    }
}

// ---------------------------------------------------------------------------
// K2: dist (B,L,Q,16) -> dA (B,L,H,QP), dtB (B,L,H,QP), Cm (B,L,QP)
// ---------------------------------------------------------------------------
__global__ __launch_bounds__(256) void k2_dist(const float* __restrict__ dist,
                                               const float* __restrict__ bias10,
                                               const float* __restrict__ W_bc,
                                               const float* __restrict__ W_dt,
                                               const float* __restrict__ dt_bias,
                                               const float* __restrict__ A_log,
                                               float* __restrict__ dA,
                                               float* __restrict__ dtB,
                                               float* __restrict__ Cm) {
    __shared__ float sWbc[32], sWdt[128], sb[8], sA[8];
    int tid = threadIdx.x;
    if (tid < 32) sWbc[tid] = W_bc[tid];
    else if (tid < 160) sWdt[tid - 32] = W_dt[tid - 32];
    else if (tid < 168) sb[tid - 160] = dt_bias[tid - 160];
    else if (tid < 176) sA[tid - 168] = -expf(A_log[tid - 168]);
    __syncthreads();
    int gid = blockIdx.x * 256 + tid;          // (b*L + l)*Q + q
    if (gid >= BB * LL * QQ) return;
    int q = gid % QQ;
    int bl = gid / QQ;
    const float* dp = dist + (size_t)gid * 16;
    float d[16];
    float4 d0 = *(const float4*)(dp + 0);
    float4 d1 = *(const float4*)(dp + 4);
    float4 d2 = *(const float4*)(dp + 8);
    float4 d3 = *(const float4*)(dp + 12);
    d[0]=d0.x; d[1]=d0.y; d[2]=d0.z; d[3]=d0.w;
    d[4]=d1.x; d[5]=d1.y; d[6]=d1.z; d[7]=d1.w;
    d[8]=d2.x; d[9]=d2.y; d[10]=d2.z; d[11]=d2.w;
    d[12]=d3.x; d[13]=d3.y; d[14]=d3.z; d[15]=d3.w;
    float bc0 = 0.f, bc1 = 0.f;
#pragma unroll
    for (int m = 0; m < 16; m++) {
        bc0 = fmaf(d[m], sWbc[m], bc0);
        bc1 = fmaf(d[m], sWbc[16 + m], bc1);
    }
    float Bmv = bc0 + bias10[bl * 10 + 0];
    float Cv  = bc1 + bias10[bl * 10 + 1];
    Cm[bl * QP + q] = Cv;
#pragma unroll
    for (int h = 0; h < 8; h++) {
        float t = 0.f;
#pragma unroll
        for (int m = 0; m < 16; m++) t = fmaf(d[m], sWdt[h * 16 + m], t);
        float pre = t + bias10[bl * 10 + 2 + h] + sb[h];
        float dt = (pre > 20.f) ? pre : log1pf(expf(pre));
        int o = (bl * 8 + h) * QP + q;
        dA[o]  = expf(sA[h] * dt);
        dtB[o] = dt * Bmv;
    }
}

// ---------------------------------------------------------------------------
// K2b: per-segment decay product  segd (B,NSEG,H,QP)
// ---------------------------------------------------------------------------
__global__ __launch_bounds__(256) void k2b_segdecay(const float* __restrict__ dA,
                                                    float* __restrict__ segd) {
    int gid = blockIdx.x * 256 + threadIdx.x;   // ((b*16+s)*8+h)*QP+q
    if (gid >= BB * NSEG * 8 * QP) return;
    int q = gid % QP; int r = gid / QP;
    int h = r % 8; r /= 8;
    int s = r % NSEG; int b = r / NSEG;
    int base = ((b * LL + s * SEGLEN) * 8 + h) * QP + q;
    float p = 1.f;
    for (int i = 0; i < SEGLEN; i++) p *= dA[base + i * 8 * QP];
    segd[gid] = p;
}

// ---------------------------------------------------------------------------
// Pass AC: SINGLE segment-local march (S_in = 0). Computes S_local (final
// local state) AND y^loc (local output). The S_in-dependent part of y is
// added later by k3_corr (affine decomposition: S_i = S_i^loc + Dcum_i*S_in).
// grid (NSEG, 32, 2), block 512 = 8 waves; wave w owns n-slice [w*40,w*40+40),
// lane = p. Operand reads are WAVE-UNIFORM (same-address LDS broadcast — the
// R4 per-lane-slice layout multiplied LDS traffic 8x and was a wash).
// G=4 staging double-buffered: [dA 0..319 | dtB ..639 | Cm ..959 | x ..1023].
// y^loc: per-wave partial to ybuf; reduced+stored one group behind.
// Plain __launch_bounds__(512): a min-waves hint in R3 spilled S[40].
// ---------------------------------------------------------------------------
__global__ __launch_bounds__(512) void pass_ac(const float* __restrict__ dA,
                                               const float* __restrict__ dtB,
                                               const float* __restrict__ Cm,
                                               const float* __restrict__ zx,
                                               float* __restrict__ S_local,
                                               float* __restrict__ yf,
                                               float* __restrict__ yb) {
    __shared__ __align__(16) float sOp[2][4][1024];
    __shared__ float ybuf[2][4][8][64];
    int seg = blockIdx.x, bh = blockIdx.y, dir = blockIdx.z;
    int tid = threadIdx.x;
    int w = tid >> 6, lane = tid & 63;
    int n0 = w * 40;
    int b = bh >> 3, h = bh & 7;
    float S[40];
#pragma unroll
    for (int j = 0; j < 40; j++) S[j] = 0.f;
    float* __restrict__ yo = dir ? yb : yf;

    auto stage = [&](int g, int buf) {
#pragma unroll
        for (int k = 0; k < 2; k++) {
            int idx = tid + k * 512;
            int it = idx >> 8;
            int pos = (idx & 255) * 4;
            int i = g * 4 + it;
            int l = dir ? (LL - 1 - (seg * SEGLEN + i)) : (seg * SEGLEN + i);
            int bl = b * LL + l;
            const float* src;
            if (pos < 320)      src = dA  + (size_t)(bl * 8 + h) * QP + pos;
            else if (pos < 640) src = dtB + (size_t)(bl * 8 + h) * QP + (pos - 320);
            else if (pos < 960) src = Cm + (size_t)bl * QP + (pos - 640);
            else                src = zx + (size_t)bl * 1024 + 512 + h * 64 + (pos - 960);
            *(float4*)&sOp[buf][it][pos] = *(const float4*)src;
        }
    };
    stage(0, 0);
    for (int g = 0; g < SEGLEN / 4; g++) {
        __syncthreads();
        if (g + 1 < SEGLEN / 4) stage(g + 1, (g + 1) & 1);
        // reduce + store previous group's y (its ybuf parity differs)
        if (g > 0 && tid < 256) {
            int it = tid >> 6, p = tid & 63;
            int i = (g - 1) * 4 + it;
            int l = dir ? (LL - 1 - (seg * SEGLEN + i)) : (seg * SEGLEN + i);
            int bl = b * LL + l;
            const float* yb0 = &ybuf[(g - 1) & 1][it][0][p];
            float t = 0.f;
#pragma unroll
            for (int ww = 0; ww < 8; ww++) t += yb0[ww * 64];
            yo[(size_t)(bl * 8 + h) * 64 + p] = t;
        }
#pragma unroll
        for (int it = 0; it < 4; it++) {
            const float* bufc = sOp[g & 1][it];
            float x = bufc[960 + lane];
            float y = 0.f;
#pragma unroll
            for (int c = 0; c < 10; c++) {
                float4 a4 = *(const float4*)(bufc + n0 + c * 4);
                float4 b4 = *(const float4*)(bufc + 320 + n0 + c * 4);
                float4 c4 = *(const float4*)(bufc + 640 + n0 + c * 4);
                S[c * 4 + 0] = fmaf(S[c * 4 + 0], a4.x, b4.x * x); y = fmaf(S[c * 4 + 0], c4.x, y);
                S[c * 4 + 1] = fmaf(S[c * 4 + 1], a4.y, b4.y * x); y = fmaf(S[c * 4 + 1], c4.y, y);
                S[c * 4 + 2] = fmaf(S[c * 4 + 2], a4.z, b4.z * x); y = fmaf(S[c * 4 + 2], c4.z, y);
                S[c * 4 + 3] = fmaf(S[c * 4 + 3], a4.w, b4.w * x); y = fmaf(S[c * 4 + 3], c4.w, y);
            }
            ybuf[g & 1][it][w][lane] = y;
        }
    }
    __syncthreads();
    // flush final group (g = 31, parity 1)
    if (tid < 256) {
        int it = tid >> 6, p = tid & 63;
        int i = (SEGLEN / 4 - 1) * 4 + it;
        int l = dir ? (LL - 1 - (seg * SEGLEN + i)) : (seg * SEGLEN + i);
        int bl = b * LL + l;
        const float* yb0 = &ybuf[1][it][0][p];
        float t = 0.f;
#pragma unroll
        for (int ww = 0; ww < 8; ww++) t += yb0[ww * 64];
        yo[(size_t)(bl * 8 + h) * 64 + p] = t;
    }
    size_t base = (size_t)((dir * NSEG + seg) * 32 + bh) * QP * 64;
#pragma unroll
    for (int j = 0; j < 40; j++)
        S_local[base + (size_t)(n0 + j) * 64 + lane] = S[j];
}

// ---------------------------------------------------------------------------
// Pass B: sequential segment combine (16 steps), writes S_in per segment and
// the averaged final state Savg (B,H,QP,P)
// ---------------------------------------------------------------------------
__global__ __launch_bounds__(256) void pass_b(const float* __restrict__ S_local,
                                              const float* __restrict__ segd,
                                              const float* __restrict__ S0q,
                                              float* __restrict__ S_in,
                                              float* __restrict__ Savg) {
    int gid = blockIdx.x * 256 + threadIdx.x;   // (b,h,n,p)
    if (gid >= BB * 8 * QP * 64) return;
    int p = gid & 63; int r = gid >> 6;
    int n = r % QP; r /= QP;
    int h = r & 7; int b = r >> 3;
    int bh = b * 8 + h;
    float s0 = (n < QQ) ? S0q[(size_t)(b * QQ + n) * 512 + h * 64 + p] : 0.f;
    float Sf = 0.f, Sb = 0.f;
    for (int dir = 0; dir < 2; dir++) {
        float S = s0;
        for (int s = 0; s < NSEG; s++) {
            size_t idx = (size_t)(((dir * NSEG + s) * 32 + bh) * QP + n) * 64 + p;
            S_in[idx] = S;
            int sf = dir ? (NSEG - 1 - s) : s;
            float dec = segd[((b * NSEG + sf) * 8 + h) * QP + n];
            S = fmaf(S, dec, S_local[idx]);
        }
        if (dir == 0) Sf = S; else Sb = S;
    }
    Savg[((bh) * QP + n) * 64 + p] = 0.5f * (Sf + Sb);
}

// ---------------------------------------------------------------------------
// K3_corr: y += Ahat @ S_in per (seg,bh,dir), where Ahat[i,n] = C_i[n] *
// cumprod_{k<=i} dA_k[n]. M=128 (steps), K=320 (n), N=64 (p).
// Block 256 = 4 waves; wave w owns i-rows [w*32, w*32+32).
// Per 32-n chunk: stage S_in chunk as split-bf16 [p][k] in LDS; cumprod dA
// (16-step per-thread chains + LDS prefix stitch), Ahat split-bf16 [i][k] in
// LDS; 3-term split MFMA. Epilogue: read-modify-write y^loc.
// ---------------------------------------------------------------------------
__global__ __launch_bounds__(256) void k3_corr(const float* __restrict__ dA,
                                               const float* __restrict__ Cm,
                                               const float* __restrict__ Sin,
                                               float* __restrict__ yf,
                                               float* __restrict__ yb) {
    __shared__ __align__(16) ushort_t sAh[128][48], sAl[128][48];  // 12 KB each
    __shared__ __align__(16) ushort_t sBh[64][48], sBl[64][48];    // 6 KB each
    __shared__ float pref[8][32];
    int seg = blockIdx.x, bh = blockIdx.y, dir = blockIdx.z;
    int b = bh >> 3, h = bh & 7;
    int tid = threadIdx.x;
    int w = tid >> 6, lane = tid & 63;
    int lm = lane & 15, lkq = lane >> 4;
    f32x4 acc[2][4];
#pragma unroll
    for (int i = 0; i < 2; i++)
#pragma unroll
        for (int j = 0; j < 4; j++) acc[i][j] = {0.f, 0.f, 0.f, 0.f};
    size_t sinBase = (size_t)((dir * NSEG + seg) * 32 + bh) * QP * 64;
    int nl = tid & 31, iseg = tid >> 5;   // cumprod roles: 32 n x 8 i-segments

    for (int k0 = 0; k0 < QP; k0 += 32) {
        __syncthreads();   // protect LDS reuse across chunks
        // ---- stage S_in chunk -> sB [p][k] split-bf16 ----
#pragma unroll
        for (int r = 0; r < 8; r++) {
            int flat = tid + r * 256;          // 0..2047
            int kn = flat >> 6, p = flat & 63;
            float v = Sin[sinBase + (size_t)(k0 + kn) * 64 + p];
            ushort_t hi, lo;
            bf16_split(v, hi, lo);
            sBh[p][kn] = hi;
            sBl[p][kn] = lo;
        }
        // ---- load dA/Cm for 16-step chain, local product ----
        float da[16], cm[16];
#pragma unroll
        for (int k = 0; k < 16; k++) {
            int i = iseg * 16 + k;
            int l = dir ? (LL - 1 - (seg * SEGLEN + i)) : (seg * SEGLEN + i);
            int bl = b * LL + l;
            da[k] = dA[(size_t)(bl * 8 + h) * QP + k0 + nl];
            cm[k] = Cm[(size_t)bl * QP + k0 + nl];
        }
        float lp = 1.f;
#pragma unroll
        for (int k = 0; k < 16; k++) lp *= da[k];
        pref[iseg][nl] = lp;
        __syncthreads();
        if (tid < 32) {                       // exclusive prefix over i-segments
            float c = 1.f;
#pragma unroll
            for (int s = 0; s < 8; s++) {
                float t = pref[s][tid];
                pref[s][tid] = c;
                c *= t;
            }
        }
        __syncthreads();
        float cum = pref[iseg][nl];
#pragma unroll
        for (int k = 0; k < 16; k++) {
            cum *= da[k];
            float v = cum * cm[k];
            ushort_t hi, lo;
            bf16_split(v, hi, lo);
            int i = iseg * 16 + k;
            sAh[i][nl] = hi;
            sAl[i][nl] = lo;
        }
        __syncthreads();
        // ---- MFMA ----
        bf16x8 ah[2], al[2], bhf[4], blf[4];
#pragma unroll
        for (int mf = 0; mf < 2; mf++) {
            int row = w * 32 + mf * 16 + lm;
            ah[mf] = *(const bf16x8*)&sAh[row][lkq * 8];
            al[mf] = *(const bf16x8*)&sAl[row][lkq * 8];
        }
#pragma unroll
        for (int nf = 0; nf < 4; nf++) {
            int p = nf * 16 + lm;
            bhf[nf] = *(const bf16x8*)&sBh[p][lkq * 8];
            blf[nf] = *(const bf16x8*)&sBl[p][lkq * 8];
        }
#pragma unroll
        for (int mf = 0; mf < 2; mf++)
#pragma unroll
            for (int nf = 0; nf < 4; nf++) {
                acc[mf][nf] = __builtin_amdgcn_mfma_f32_16x16x32_bf16(ah[mf], bhf[nf], acc[mf][nf], 0, 0, 0);
                acc[mf][nf] = __builtin_amdgcn_mfma_f32_16x16x32_bf16(ah[mf], blf[nf], acc[mf][nf], 0, 0, 0);
                acc[mf][nf] = __builtin_amdgcn_mfma_f32_16x16x32_bf16(al[mf], bhf[nf], acc[mf][nf], 0, 0, 0);
            }
    }
    // ---- epilogue: y += correction ----
    float* __restrict__ yo = dir ? yb : yf;
#pragma unroll
    for (int mf = 0; mf < 2; mf++)
#pragma unroll
        for (int nf = 0; nf < 4; nf++)
#pragma unroll
            for (int r = 0; r < 4; r++) {
                int i = w * 32 + mf * 16 + lkq * 4 + r;
                int p = nf * 16 + lm;
                int l = dir ? (LL - 1 - (seg * SEGLEN + i)) : (seg * SEGLEN + i);
                size_t idx = (size_t)((b * LL + l) * 8 + h) * 64 + p;
                yo[idx] += acc[mf][nf][r];
            }
}

// ---------------------------------------------------------------------------
// K4: y = 0.5*(yf+yb) + Dp*x ; g = y*silu(z) ; key = g * rms(g) * key_norm_w
// ---------------------------------------------------------------------------
__global__ __launch_bounds__(512) void k4_gate(const float* __restrict__ yf,
                                               const float* __restrict__ yb,
                                               const float* __restrict__ zx,
                                               const float* __restrict__ Dp,
                                               const float* __restrict__ knw,
                                               float* __restrict__ key) {
    int bl = blockIdx.x;
    int t = threadIdx.x;
    int h = t >> 6;
    float x = zx[(size_t)bl * 1024 + 512 + t];
    float yv = 0.5f * (yf[(size_t)bl * 512 + t] + yb[(size_t)bl * 512 + t]) + Dp[h] * x;
    float z = zx[(size_t)bl * 1024 + t];
    float g = yv * (z / (1.f + expf(-z)));
    float v = g * g;
#pragma unroll
    for (int o = 32; o > 0; o >>= 1) v += __shfl_down(v, o, 64);
    __shared__ float rs[8];
    __shared__ float stot;
    if ((t & 63) == 0) rs[t >> 6] = v;
    __syncthreads();
    if (t == 0) {
        float s = 0.f;
#pragma unroll
        for (int i = 0; i < 8; i++) s += rs[i];
        stot = s;
    }
    __syncthreads();
    float rms = rsqrtf(stot / 512.f + 1e-5f);
    key[(size_t)bl * 512 + t] = g * rms * knw[t];
}

// ---------------------------------------------------------------------------
// K5: layernorm on Savg rearranged to (B,Q,512); one block per (b,q)
// ---------------------------------------------------------------------------
__global__ __launch_bounds__(512) void k5_ln(const float* __restrict__ Savg,
                                             const float* __restrict__ lnw,
                                             const float* __restrict__ lnb,
                                             float* __restrict__ lsn) {
    int bq = blockIdx.x;
    int b = bq / QQ, q = bq % QQ;
    int t = threadIdx.x;
    int h = t >> 6, p = t & 63;
    float v = Savg[((b * 8 + h) * QP + q) * 64 + p];
    float s1 = v, s2 = v * v;
#pragma unroll
    for (int o = 32; o > 0; o >>= 1) {
        s1 += __shfl_down(s1, o, 64);
        s2 += __shfl_down(s2, o, 64);
    }
    __shared__ float r1[8], r2[8];
    __shared__ float smu, srv;
    if ((t & 63) == 0) { r1[t >> 6] = s1; r2[t >> 6] = s2; }
    __syncthreads();
    if (t == 0) {
        float a = 0.f, c = 0.f;
#pragma unroll
        for (int i = 0; i < 8; i++) { a += r1[i]; c += r2[i]; }
        float mu = a / 512.f;
        float var = c / 512.f - mu * mu;
        smu = mu;
        srv = rsqrtf(var + 1e-5f);
    }
    __syncthreads();
    lsn[(size_t)bq * 512 + t] = (v - smu) * srv * lnw[t] + lnb[t];
}

// ---------------------------------------------------------------------------
extern "C" void kernel_launch(void* const* d_in, const int* in_sizes, int n_in,
                              void* d_out, int out_size, void* d_ws, size_t ws_size,
                              hipStream_t stream) {
    const float* in_key    = (const float*)d_in[0];
    const float* in_query  = (const float*)d_in[1];
    const float* dist      = (const float*)d_in[2];
    const float* W_key     = (const float*)d_in[3];
    const float* W_query   = (const float*)d_in[4];
    const float* W_bc      = (const float*)d_in[5];
    const float* W_dt      = (const float*)d_in[6];
    const float* dt_bias   = (const float*)d_in[7];
    const float* A_log     = (const float*)d_in[8];
    const float* Dp        = (const float*)d_in[9];
    const float* W_out_key = (const float*)d_in[10];
    const float* W_out_query = (const float*)d_in[11];
    const float* key_norm_w = (const float*)d_in[12];
    const float* ln_w      = (const float*)d_in[13];
    const float* ln_b      = (const float*)d_in[14];

    float* out_key = (float*)d_out;
    float* out_query = out_key + (size_t)BB * LL * D_MODEL;   // 2,097,152

    char* w8 = (char*)d_ws;
    auto alloc = [&](size_t bytes) {
        char* ptr = w8;
        w8 += (bytes + 255) & ~(size_t)255;
        return ptr;
    };
    float* zx     = (float*)alloc((size_t)8192 * 1024 * 4);
    float* bias10 = (float*)alloc((size_t)8192 * 10 * 4);
    float* S0q    = (float*)alloc((size_t)1200 * 512 * 4);
    float* dAb    = (float*)alloc((size_t)8192 * 8 * QP * 4);
    float* dtBb   = (float*)alloc((size_t)8192 * 8 * QP * 4);
    float* Cmb    = (float*)alloc((size_t)8192 * QP * 4);
    float* segd   = (float*)alloc((size_t)BB * NSEG * 8 * QP * 4);
    float* Sloc   = (float*)alloc((size_t)2 * NSEG * 32 * QP * 64 * 4);
    float* Sin    = (float*)alloc((size_t)2 * NSEG * 32 * QP * 64 * 4);
    float* yfb    = (float*)alloc((size_t)8192 * 512 * 4);
    float* ybb    = (float*)alloc((size_t)8192 * 512 * 4);
    float* Savg   = (float*)alloc((size_t)32 * QP * 64 * 4);
    float* keyb   = (float*)alloc((size_t)8192 * 512 * 4);
    float* lsn    = (float*)alloc((size_t)1200 * 512 * 4);
    ushort_t* ink_h  = (ushort_t*)alloc((size_t)2097152 * 2);
    ushort_t* ink_l  = (ushort_t*)alloc((size_t)2097152 * 2);
    ushort_t* wk_h   = (ushort_t*)alloc((size_t)262144 * 2);
    ushort_t* wk_l   = (ushort_t*)alloc((size_t)262144 * 2);
    ushort_t* inq_h  = (ushort_t*)alloc((size_t)307200 * 2);
    ushort_t* inq_l  = (ushort_t*)alloc((size_t)307200 * 2);
    ushort_t* wq_h   = (ushort_t*)alloc((size_t)131072 * 2);
    ushort_t* wq_l   = (ushort_t*)alloc((size_t)131072 * 2);
    ushort_t* keyb_h = (ushort_t*)alloc((size_t)4194304 * 2);
    ushort_t* keyb_l = (ushort_t*)alloc((size_t)4194304 * 2);
    ushort_t* wok_h  = (ushort_t*)alloc((size_t)131072 * 2);
    ushort_t* wok_l  = (ushort_t*)alloc((size_t)131072 * 2);
    ushort_t* lsn_h  = (ushort_t*)alloc((size_t)614400 * 2);
    ushort_t* lsn_l  = (ushort_t*)alloc((size_t)614400 * 2);
    ushort_t* woq_h  = (ushort_t*)alloc((size_t)131072 * 2);
    ushort_t* woq_l  = (ushort_t*)alloc((size_t)131072 * 2);

    // Input conversions (bf16 hi/lo)
    c_split<<<8192, 256, 0, stream>>>(in_key, ink_h, ink_l, 2097152);
    c_split<<<1024, 256, 0, stream>>>(W_key, wk_h, wk_l, 262144);       // rows 0..1023
    c_split<<<1200, 256, 0, stream>>>(in_query, inq_h, inq_l, 307200);
    c_split<<<512, 256, 0, stream>>>(W_query, wq_h, wq_l, 131072);
    c_split<<<512, 256, 0, stream>>>(W_out_key, wok_h, wok_l, 131072);
    c_split<<<512, 256, 0, stream>>>(W_out_query, woq_h, woq_l, 131072);

    // Projections
    gemm_bf16s<<<dim3(16, 64), 256, 0, stream>>>(ink_h, ink_l, wk_h, wk_l, zx, 8192, 1024, 256);
    k1b_bias<<<2048, 256, 0, stream>>>(in_key, W_key, bias10);
    gemm_bf16s<<<dim3(8, 10), 256, 0, stream>>>(inq_h, inq_l, wq_h, wq_l, S0q, 1200, 512, 256);

    // dist -> dA, dtB, Cm
    k2_dist<<<9600, 256, 0, stream>>>(dist, bias10, W_bc, W_dt, dt_bias, A_log, dAb, dtBb, Cmb);
    k2b_segdecay<<<640, 256, 0, stream>>>(dAb, segd);

    // segmented bidirectional scan: single march + combine + MFMA correction
    pass_ac<<<dim3(NSEG, 32, 2), 512, 0, stream>>>(dAb, dtBb, Cmb, zx, Sloc, yfb, ybb);
    pass_b<<<2560, 256, 0, stream>>>(Sloc, segd, S0q, Sin, Savg);
    k3_corr<<<dim3(NSEG, 32, 2), 256, 0, stream>>>(dAb, Cmb, Sin, yfb, ybb);

    // out_key path
    k4_gate<<<8192, 512, 0, stream>>>(yfb, ybb, zx, Dp, key_norm_w, keyb);
    c_split<<<16384, 256, 0, stream>>>(keyb, keyb_h, keyb_l, 4194304);
    gemm_bf16s<<<dim3(4, 64), 256, 0, stream>>>(keyb_h, keyb_l, wok_h, wok_l, out_key, 8192, 256, 512);

    // out_query path
    k5_ln<<<1200, 512, 0, stream>>>(Savg, ln_w, ln_b, lsn);
    c_split<<<2400, 256, 0, stream>>>(lsn, lsn_h, lsn_l, 614400);
    gemm_bf16s<<<dim3(4, 10), 256, 0, stream>>>(lsn_h, lsn_l, woq_h, woq_l, out_query, 1200, 256, 512);
}

// Round 6
// 893.490 us; speedup vs baseline: 1.3829x; 1.0031x over previous
//
#include <hip/hip_runtime.h>
#include <hip/hip_bf16.h>

// Problem constants
#define D_MODEL 256
#define D_INNER 512
#define NHEADS 8
#define HEADDIM 64
#define MDIST 16
#define BB 4
#define LL 2048
#define QQ 300
#define QP 320          // padded Q; wave w of 8 owns n-slice [w*40, w*40+40)
#define NSEG 16
#define SEGLEN 128      // LL / NSEG

typedef unsigned short ushort_t;
typedef __attribute__((ext_vector_type(8))) short bf16x8;
typedef __attribute__((ext_vector_type(4))) float f32x4;

__device__ __forceinline__ void bf16_split(float v, ushort_t& hi, ushort_t& lo) {
    __hip_bfloat16 h = __float2bfloat16(v);
    float hf = __bfloat162float(h);
    __hip_bfloat16 l = __float2bfloat16(v - hf);
    hi = *(ushort_t*)&h;
    lo = *(ushort_t*)&l;
}

// ---------------------------------------------------------------------------
// Split fp32 -> bf16 hi + bf16 lo (residual). C = Ah*Bh + Ah*Bl + Al*Bh gives
// ~fp32 accuracy (missing Al*Bl term ~2^-18 relative).
// ---------------------------------------------------------------------------
__global__ __launch_bounds__(256) void c_split(const float* __restrict__ in,
                                               ushort_t* __restrict__ hi,
                                               ushort_t* __restrict__ lo, int n) {
    int i = blockIdx.x * 256 + threadIdx.x;
    if (i >= n) return;
    ushort_t h, l;
    bf16_split(in[i], h, l);
    hi[i] = h;
    lo[i] = l;
}

// ---------------------------------------------------------------------------
// Split-bf16 MFMA GEMM: C[M,N] = A[M,K] * B[N,K]^T (NT), fp32 out.
// mfma_f32_16x16x32_bf16 layout (m89-verified):
//   A[m=lane&15][k=(lane>>4)*8+j]; B[k=(lane>>4)*8+j][n=lane&15];
//   D[row=(lane>>4)*4+r][col=lane&15].
// ---------------------------------------------------------------------------
__global__ __launch_bounds__(256) void gemm_bf16s(const ushort_t* __restrict__ Ah,
                                                  const ushort_t* __restrict__ Al,
                                                  const ushort_t* __restrict__ Bh,
                                                  const ushort_t* __restrict__ Bl,
                                                  float* __restrict__ C,
                                                  int M, int N, int K) {
    int w = threadIdx.x >> 6, lane = threadIdx.x & 63;
    int n0 = blockIdx.x * 64;
    int m0 = blockIdx.y * 128 + w * 32;
    int lm = lane & 15, lk = (lane >> 4) * 8;
    f32x4 acc[2][4];
#pragma unroll
    for (int i = 0; i < 2; i++)
#pragma unroll
        for (int j = 0; j < 4; j++) acc[i][j] = {0.f, 0.f, 0.f, 0.f};

    for (int k0 = 0; k0 < K; k0 += 32) {
        bf16x8 ah[2], al[2], bh[4], blo[4];
#pragma unroll
        for (int mf = 0; mf < 2; mf++) {
            int row = m0 + mf * 16 + lm;
            if (row >= M) row = M - 1;            // safe clamp; epilogue guards
            size_t off = (size_t)row * K + k0 + lk;
            ah[mf] = *(const bf16x8*)(Ah + off);
            al[mf] = *(const bf16x8*)(Al + off);
        }
#pragma unroll
        for (int nf = 0; nf < 4; nf++) {
            int col = n0 + nf * 16 + lm;
            size_t off = (size_t)col * K + k0 + lk;
            bh[nf]  = *(const bf16x8*)(Bh + off);
            blo[nf] = *(const bf16x8*)(Bl + off);
        }
#pragma unroll
        for (int mf = 0; mf < 2; mf++)
#pragma unroll
            for (int nf = 0; nf < 4; nf++) {
                acc[mf][nf] = __builtin_amdgcn_mfma_f32_16x16x32_bf16(ah[mf], bh[nf],  acc[mf][nf], 0, 0, 0);
                acc[mf][nf] = __builtin_amdgcn_mfma_f32_16x16x32_bf16(ah[mf], blo[nf], acc[mf][nf], 0, 0, 0);
                acc[mf][nf] = __builtin_amdgcn_mfma_f32_16x16x32_bf16(al[mf], bh[nf],  acc[mf][nf], 0, 0, 0);
            }
    }
#pragma unroll
    for (int mf = 0; mf < 2; mf++)
#pragma unroll
        for (int nf = 0; nf < 4; nf++)
#pragma unroll
            for (int r = 0; r < 4; r++) {
                int m = m0 + mf * 16 + (lane >> 4) * 4 + r;
                if (m < M) C[(size_t)m * N + n0 + nf * 16 + lm] = acc[mf][nf][r];
            }
}

// ---------------------------------------------------------------------------
// K1b: fp32 bias columns (rows 1024..1033 of W_key) — precision-critical.
// ---------------------------------------------------------------------------
__global__ __launch_bounds__(256) void k1b_bias(const float* __restrict__ in_key,
                                                const float* __restrict__ W_key,
                                                float* __restrict__ bias10) {
    int w = threadIdx.x >> 6, lane = threadIdx.x & 63;
    int row = blockIdx.x * 4 + w;
    float4 a = *(const float4*)(in_key + (size_t)row * 256 + lane * 4);
#pragma unroll
    for (int c = 0; c < 10; c++) {
        float4 b = *(const float4*)(W_key + (size_t)(1024 + c) * 256 + lane * 4);
        float t = a.x * b.x + a.y * b.y + a.z * b.z + a.w * b.w;
#pragma unroll
        for (int o = 32; o > 0; o >>= 1) t += __shfl_down(t, o, 64);
        if (lane == 0) bias10[row * 10 + c] = t;
    }
}

// ---------------------------------------------------------------------------
// K2: dist (B,L,Q,16) -> dA (B,L,H,QP), dtB (B,L,H,QP), Cm (B,L,QP)
// ---------------------------------------------------------------------------
__global__ __launch_bounds__(256) void k2_dist(const float* __restrict__ dist,
                                               const float* __restrict__ bias10,
                                               const float* __restrict__ W_bc,
                                               const float* __restrict__ W_dt,
                                               const float* __restrict__ dt_bias,
                                               const float* __restrict__ A_log,
                                               float* __restrict__ dA,
                                               float* __restrict__ dtB,
                                               float* __restrict__ Cm) {
    __shared__ float sWbc[32], sWdt[128], sb[8], sA[8];
    int tid = threadIdx.x;
    if (tid < 32) sWbc[tid] = W_bc[tid];
    else if (tid < 160) sWdt[tid - 32] = W_dt[tid - 32];
    else if (tid < 168) sb[tid - 160] = dt_bias[tid - 160];
    else if (tid < 176) sA[tid - 168] = -expf(A_log[tid - 168]);
    __syncthreads();
    int gid = blockIdx.x * 256 + tid;          // (b*L + l)*Q + q
    if (gid >= BB * LL * QQ) return;
    int q = gid % QQ;
    int bl = gid / QQ;
    const float* dp = dist + (size_t)gid * 16;
    float d[16];
    float4 d0 = *(const float4*)(dp + 0);
    float4 d1 = *(const float4*)(dp + 4);
    float4 d2 = *(const float4*)(dp + 8);
    float4 d3 = *(const float4*)(dp + 12);
    d[0]=d0.x; d[1]=d0.y; d[2]=d0.z; d[3]=d0.w;
    d[4]=d1.x; d[5]=d1.y; d[6]=d1.z; d[7]=d1.w;
    d[8]=d2.x; d[9]=d2.y; d[10]=d2.z; d[11]=d2.w;
    d[12]=d3.x; d[13]=d3.y; d[14]=d3.z; d[15]=d3.w;
    float bc0 = 0.f, bc1 = 0.f;
#pragma unroll
    for (int m = 0; m < 16; m++) {
        bc0 = fmaf(d[m], sWbc[m], bc0);
        bc1 = fmaf(d[m], sWbc[16 + m], bc1);
    }
    float Bmv = bc0 + bias10[bl * 10 + 0];
    float Cv  = bc1 + bias10[bl * 10 + 1];
    Cm[bl * QP + q] = Cv;
#pragma unroll
    for (int h = 0; h < 8; h++) {
        float t = 0.f;
#pragma unroll
        for (int m = 0; m < 16; m++) t = fmaf(d[m], sWdt[h * 16 + m], t);
        float pre = t + bias10[bl * 10 + 2 + h] + sb[h];
        float dt = (pre > 20.f) ? pre : log1pf(expf(pre));
        int o = (bl * 8 + h) * QP + q;
        dA[o]  = expf(sA[h] * dt);
        dtB[o] = dt * Bmv;
    }
}

// ---------------------------------------------------------------------------
// K2b: per-segment decay product  segd (B,NSEG,H,QP)
// ---------------------------------------------------------------------------
__global__ __launch_bounds__(256) void k2b_segdecay(const float* __restrict__ dA,
                                                    float* __restrict__ segd) {
    int gid = blockIdx.x * 256 + threadIdx.x;   // ((b*16+s)*8+h)*QP+q
    if (gid >= BB * NSEG * 8 * QP) return;
    int q = gid % QP; int r = gid / QP;
    int h = r % 8; r /= 8;
    int s = r % NSEG; int b = r / NSEG;
    int base = ((b * LL + s * SEGLEN) * 8 + h) * QP + q;
    float p = 1.f;
    for (int i = 0; i < SEGLEN; i++) p *= dA[base + i * 8 * QP];
    segd[gid] = p;
}

// ---------------------------------------------------------------------------
// Pass AC: SINGLE segment-local march (S_in = 0). Computes S_local (final
// local state) AND y^loc. Inter-segment part added by k3_corr (affine:
// S_i = S_i^loc + Dcum_i*S_in).
// grid (NSEG, 32, 2), block 512 = 8 waves; wave w owns n-slice [w*40,w*40+40),
// lane = p. Operand reads WAVE-UNIFORM (LDS same-address broadcast).
// G=2 staging double-buffered: [dA 0..319 | dtB ..639 | Cm ..959 | x ..1023].
// LDS total 24 KB (R5's 48 KB capped co-residency at 3 blocks/CU for a grid
// of exactly 4/CU -> Occupancy 41%; 24 KB allows all 4 resident so barrier
// drains of one block hide under compute of the others).
// Plain __launch_bounds__(512): a min-waves hint in R3 spilled S[40].
// ---------------------------------------------------------------------------
__global__ __launch_bounds__(512) void pass_ac(const float* __restrict__ dA,
                                               const float* __restrict__ dtB,
                                               const float* __restrict__ Cm,
                                               const float* __restrict__ zx,
                                               float* __restrict__ S_local,
                                               float* __restrict__ yf,
                                               float* __restrict__ yb) {
    __shared__ __align__(16) float sOp[2][2][1024];   // 16 KB
    __shared__ float ybuf[2][2][8][64];               //  8 KB
    int seg = blockIdx.x, bh = blockIdx.y, dir = blockIdx.z;
    int tid = threadIdx.x;
    int w = tid >> 6, lane = tid & 63;
    int n0 = w * 40;
    int b = bh >> 3, h = bh & 7;
    float S[40];
#pragma unroll
    for (int j = 0; j < 40; j++) S[j] = 0.f;
    float* __restrict__ yo = dir ? yb : yf;

    auto stage = [&](int g, int buf) {
        int it = tid >> 8;              // 0..1
        int pos = (tid & 255) * 4;
        int i = g * 2 + it;
        int l = dir ? (LL - 1 - (seg * SEGLEN + i)) : (seg * SEGLEN + i);
        int bl = b * LL + l;
        const float* src;
        if (pos < 320)      src = dA  + (size_t)(bl * 8 + h) * QP + pos;
        else if (pos < 640) src = dtB + (size_t)(bl * 8 + h) * QP + (pos - 320);
        else if (pos < 960) src = Cm + (size_t)bl * QP + (pos - 640);
        else                src = zx + (size_t)bl * 1024 + 512 + h * 64 + (pos - 960);
        *(float4*)&sOp[buf][it][pos] = *(const float4*)src;
    };
    stage(0, 0);
    const int NG = SEGLEN / 2;          // 64 groups of 2 steps
    for (int g = 0; g < NG; g++) {
        __syncthreads();
        if (g + 1 < NG) stage(g + 1, (g + 1) & 1);
        // reduce + store previous group's y (opposite ybuf parity: no hazard)
        if (g > 0 && tid < 128) {
            int it = tid >> 6, p = tid & 63;
            int i = (g - 1) * 2 + it;
            int l = dir ? (LL - 1 - (seg * SEGLEN + i)) : (seg * SEGLEN + i);
            int bl = b * LL + l;
            const float* yb0 = &ybuf[(g - 1) & 1][it][0][p];
            float t = 0.f;
#pragma unroll
            for (int ww = 0; ww < 8; ww++) t += yb0[ww * 64];
            yo[(size_t)(bl * 8 + h) * 64 + p] = t;
        }
#pragma unroll
        for (int it = 0; it < 2; it++) {
            const float* bufc = sOp[g & 1][it];
            float x = bufc[960 + lane];
            float y = 0.f;
#pragma unroll
            for (int c = 0; c < 10; c++) {
                float4 a4 = *(const float4*)(bufc + n0 + c * 4);
                float4 b4 = *(const float4*)(bufc + 320 + n0 + c * 4);
                float4 c4 = *(const float4*)(bufc + 640 + n0 + c * 4);
                S[c * 4 + 0] = fmaf(S[c * 4 + 0], a4.x, b4.x * x); y = fmaf(S[c * 4 + 0], c4.x, y);
                S[c * 4 + 1] = fmaf(S[c * 4 + 1], a4.y, b4.y * x); y = fmaf(S[c * 4 + 1], c4.y, y);
                S[c * 4 + 2] = fmaf(S[c * 4 + 2], a4.z, b4.z * x); y = fmaf(S[c * 4 + 2], c4.z, y);
                S[c * 4 + 3] = fmaf(S[c * 4 + 3], a4.w, b4.w * x); y = fmaf(S[c * 4 + 3], c4.w, y);
            }
            ybuf[g & 1][it][w][lane] = y;
        }
    }
    __syncthreads();
    // flush final group (g = NG-1, parity (NG-1)&1 = 1)
    if (tid < 128) {
        int it = tid >> 6, p = tid & 63;
        int i = (NG - 1) * 2 + it;
        int l = dir ? (LL - 1 - (seg * SEGLEN + i)) : (seg * SEGLEN + i);
        int bl = b * LL + l;
        const float* yb0 = &ybuf[1][it][0][p];
        float t = 0.f;
#pragma unroll
        for (int ww = 0; ww < 8; ww++) t += yb0[ww * 64];
        yo[(size_t)(bl * 8 + h) * 64 + p] = t;
    }
    size_t base = (size_t)((dir * NSEG + seg) * 32 + bh) * QP * 64;
#pragma unroll
    for (int j = 0; j < 40; j++)
        S_local[base + (size_t)(n0 + j) * 64 + lane] = S[j];
}

// ---------------------------------------------------------------------------
// Pass B: sequential segment combine (16 steps), writes S_in per segment and
// the averaged final state Savg (B,H,QP,P)
// ---------------------------------------------------------------------------
__global__ __launch_bounds__(256) void pass_b(const float* __restrict__ S_local,
                                              const float* __restrict__ segd,
                                              const float* __restrict__ S0q,
                                              float* __restrict__ S_in,
                                              float* __restrict__ Savg) {
    int gid = blockIdx.x * 256 + threadIdx.x;   // (b,h,n,p)
    if (gid >= BB * 8 * QP * 64) return;
    int p = gid & 63; int r = gid >> 6;
    int n = r % QP; r /= QP;
    int h = r & 7; int b = r >> 3;
    int bh = b * 8 + h;
    float s0 = (n < QQ) ? S0q[(size_t)(b * QQ + n) * 512 + h * 64 + p] : 0.f;
    float Sf = 0.f, Sb = 0.f;
    for (int dir = 0; dir < 2; dir++) {
        float S = s0;
        for (int s = 0; s < NSEG; s++) {
            size_t idx = (size_t)(((dir * NSEG + s) * 32 + bh) * QP + n) * 64 + p;
            S_in[idx] = S;
            int sf = dir ? (NSEG - 1 - s) : s;
            float dec = segd[((b * NSEG + sf) * 8 + h) * QP + n];
            S = fmaf(S, dec, S_local[idx]);
        }
        if (dir == 0) Sf = S; else Sb = S;
    }
    Savg[((bh) * QP + n) * 64 + p] = 0.5f * (Sf + Sb);
}

// ---------------------------------------------------------------------------
// K3_corr: y += Ahat @ S_in per (seg,bh,dir), where Ahat[i,n] = C_i[n] *
// cumprod_{k<=i} dA_k[n]. M=128 (steps), K=320 (n), N=64 (p).
// ---------------------------------------------------------------------------
__global__ __launch_bounds__(256) void k3_corr(const float* __restrict__ dA,
                                               const float* __restrict__ Cm,
                                               const float* __restrict__ Sin,
                                               float* __restrict__ yf,
                                               float* __restrict__ yb) {
    __shared__ __align__(16) ushort_t sAh[128][48], sAl[128][48];  // 12 KB each
    __shared__ __align__(16) ushort_t sBh[64][48], sBl[64][48];    // 6 KB each
    __shared__ float pref[8][32];
    int seg = blockIdx.x, bh = blockIdx.y, dir = blockIdx.z;
    int b = bh >> 3, h = bh & 7;
    int tid = threadIdx.x;
    int w = tid >> 6, lane = tid & 63;
    int lm = lane & 15, lkq = lane >> 4;
    f32x4 acc[2][4];
#pragma unroll
    for (int i = 0; i < 2; i++)
#pragma unroll
        for (int j = 0; j < 4; j++) acc[i][j] = {0.f, 0.f, 0.f, 0.f};
    size_t sinBase = (size_t)((dir * NSEG + seg) * 32 + bh) * QP * 64;
    int nl = tid & 31, iseg = tid >> 5;   // cumprod roles: 32 n x 8 i-segments

    for (int k0 = 0; k0 < QP; k0 += 32) {
        __syncthreads();   // protect LDS reuse across chunks
        // ---- stage S_in chunk -> sB [p][k] split-bf16 ----
#pragma unroll
        for (int r = 0; r < 8; r++) {
            int flat = tid + r * 256;          // 0..2047
            int kn = flat >> 6, p = flat & 63;
            float v = Sin[sinBase + (size_t)(k0 + kn) * 64 + p];
            ushort_t hi, lo;
            bf16_split(v, hi, lo);
            sBh[p][kn] = hi;
            sBl[p][kn] = lo;
        }
        // ---- load dA/Cm for 16-step chain, local product ----
        float da[16], cm[16];
#pragma unroll
        for (int k = 0; k < 16; k++) {
            int i = iseg * 16 + k;
            int l = dir ? (LL - 1 - (seg * SEGLEN + i)) : (seg * SEGLEN + i);
            int bl = b * LL + l;
            da[k] = dA[(size_t)(bl * 8 + h) * QP + k0 + nl];
            cm[k] = Cm[(size_t)bl * QP + k0 + nl];
        }
        float lp = 1.f;
#pragma unroll
        for (int k = 0; k < 16; k++) lp *= da[k];
        pref[iseg][nl] = lp;
        __syncthreads();
        if (tid < 32) {                       // exclusive prefix over i-segments
            float c = 1.f;
#pragma unroll
            for (int s = 0; s < 8; s++) {
                float t = pref[s][tid];
                pref[s][tid] = c;
                c *= t;
            }
        }
        __syncthreads();
        float cum = pref[iseg][nl];
#pragma unroll
        for (int k = 0; k < 16; k++) {
            cum *= da[k];
            float v = cum * cm[k];
            ushort_t hi, lo;
            bf16_split(v, hi, lo);
            int i = iseg * 16 + k;
            sAh[i][nl] = hi;
            sAl[i][nl] = lo;
        }
        __syncthreads();
        // ---- MFMA ----
        bf16x8 ah[2], al[2], bhf[4], blf[4];
#pragma unroll
        for (int mf = 0; mf < 2; mf++) {
            int row = w * 32 + mf * 16 + lm;
            ah[mf] = *(const bf16x8*)&sAh[row][lkq * 8];
            al[mf] = *(const bf16x8*)&sAl[row][lkq * 8];
        }
#pragma unroll
        for (int nf = 0; nf < 4; nf++) {
            int p = nf * 16 + lm;
            bhf[nf] = *(const bf16x8*)&sBh[p][lkq * 8];
            blf[nf] = *(const bf16x8*)&sBl[p][lkq * 8];
        }
#pragma unroll
        for (int mf = 0; mf < 2; mf++)
#pragma unroll
            for (int nf = 0; nf < 4; nf++) {
                acc[mf][nf] = __builtin_amdgcn_mfma_f32_16x16x32_bf16(ah[mf], bhf[nf], acc[mf][nf], 0, 0, 0);
                acc[mf][nf] = __builtin_amdgcn_mfma_f32_16x16x32_bf16(ah[mf], blf[nf], acc[mf][nf], 0, 0, 0);
                acc[mf][nf] = __builtin_amdgcn_mfma_f32_16x16x32_bf16(al[mf], bhf[nf], acc[mf][nf], 0, 0, 0);
            }
    }
    // ---- epilogue: y += correction ----
    float* __restrict__ yo = dir ? yb : yf;
#pragma unroll
    for (int mf = 0; mf < 2; mf++)
#pragma unroll
        for (int nf = 0; nf < 4; nf++)
#pragma unroll
            for (int r = 0; r < 4; r++) {
                int i = w * 32 + mf * 16 + lkq * 4 + r;
                int p = nf * 16 + lm;
                int l = dir ? (LL - 1 - (seg * SEGLEN + i)) : (seg * SEGLEN + i);
                size_t idx = (size_t)((b * LL + l) * 8 + h) * 64 + p;
                yo[idx] += acc[mf][nf][r];
            }
}

// ---------------------------------------------------------------------------
// K4: y = 0.5*(yf+yb) + Dp*x ; g = y*silu(z) ; key = g * rms(g) * key_norm_w
// Fused epilogue: writes key directly as split-bf16 (kh/kl) for the out GEMM.
// ---------------------------------------------------------------------------
__global__ __launch_bounds__(512) void k4_gate(const float* __restrict__ yf,
                                               const float* __restrict__ yb,
                                               const float* __restrict__ zx,
                                               const float* __restrict__ Dp,
                                               const float* __restrict__ knw,
                                               ushort_t* __restrict__ kh,
                                               ushort_t* __restrict__ kl) {
    int bl = blockIdx.x;
    int t = threadIdx.x;
    int h = t >> 6;
    float x = zx[(size_t)bl * 1024 + 512 + t];
    float yv = 0.5f * (yf[(size_t)bl * 512 + t] + yb[(size_t)bl * 512 + t]) + Dp[h] * x;
    float z = zx[(size_t)bl * 1024 + t];
    float g = yv * (z / (1.f + expf(-z)));
    float v = g * g;
#pragma unroll
    for (int o = 32; o > 0; o >>= 1) v += __shfl_down(v, o, 64);
    __shared__ float rs[8];
    __shared__ float stot;
    if ((t & 63) == 0) rs[t >> 6] = v;
    __syncthreads();
    if (t == 0) {
        float s = 0.f;
#pragma unroll
        for (int i = 0; i < 8; i++) s += rs[i];
        stot = s;
    }
    __syncthreads();
    float rms = rsqrtf(stot / 512.f + 1e-5f);
    float kv = g * rms * knw[t];
    ushort_t hi, lo;
    bf16_split(kv, hi, lo);
    kh[(size_t)bl * 512 + t] = hi;
    kl[(size_t)bl * 512 + t] = lo;
}

// ---------------------------------------------------------------------------
// K5: layernorm on Savg rearranged to (B,Q,512); one block per (b,q).
// Fused epilogue: split-bf16 output.
// ---------------------------------------------------------------------------
__global__ __launch_bounds__(512) void k5_ln(const float* __restrict__ Savg,
                                             const float* __restrict__ lnw,
                                             const float* __restrict__ lnb,
                                             ushort_t* __restrict__ lh,
                                             ushort_t* __restrict__ ll) {
    int bq = blockIdx.x;
    int b = bq / QQ, q = bq % QQ;
    int t = threadIdx.x;
    int h = t >> 6, p = t & 63;
    float v = Savg[((b * 8 + h) * QP + q) * 64 + p];
    float s1 = v, s2 = v * v;
#pragma unroll
    for (int o = 32; o > 0; o >>= 1) {
        s1 += __shfl_down(s1, o, 64);
        s2 += __shfl_down(s2, o, 64);
    }
    __shared__ float r1[8], r2[8];
    __shared__ float smu, srv;
    if ((t & 63) == 0) { r1[t >> 6] = s1; r2[t >> 6] = s2; }
    __syncthreads();
    if (t == 0) {
        float a = 0.f, c = 0.f;
#pragma unroll
        for (int i = 0; i < 8; i++) { a += r1[i]; c += r2[i]; }
        float mu = a / 512.f;
        float var = c / 512.f - mu * mu;
        smu = mu;
        srv = rsqrtf(var + 1e-5f);
    }
    __syncthreads();
    float ov = (v - smu) * srv * lnw[t] + lnb[t];
    ushort_t hi, lo;
    bf16_split(ov, hi, lo);
    lh[(size_t)bq * 512 + t] = hi;
    ll[(size_t)bq * 512 + t] = lo;
}

// ---------------------------------------------------------------------------
extern "C" void kernel_launch(void* const* d_in, const int* in_sizes, int n_in,
                              void* d_out, int out_size, void* d_ws, size_t ws_size,
                              hipStream_t stream) {
    const float* in_key    = (const float*)d_in[0];
    const float* in_query  = (const float*)d_in[1];
    const float* dist      = (const float*)d_in[2];
    const float* W_key     = (const float*)d_in[3];
    const float* W_query   = (const float*)d_in[4];
    const float* W_bc      = (const float*)d_in[5];
    const float* W_dt      = (const float*)d_in[6];
    const float* dt_bias   = (const float*)d_in[7];
    const float* A_log     = (const float*)d_in[8];
    const float* Dp        = (const float*)d_in[9];
    const float* W_out_key = (const float*)d_in[10];
    const float* W_out_query = (const float*)d_in[11];
    const float* key_norm_w = (const float*)d_in[12];
    const float* ln_w      = (const float*)d_in[13];
    const float* ln_b      = (const float*)d_in[14];

    float* out_key = (float*)d_out;
    float* out_query = out_key + (size_t)BB * LL * D_MODEL;   // 2,097,152

    char* w8 = (char*)d_ws;
    auto alloc = [&](size_t bytes) {
        char* ptr = w8;
        w8 += (bytes + 255) & ~(size_t)255;
        return ptr;
    };
    float* zx     = (float*)alloc((size_t)8192 * 1024 * 4);
    float* bias10 = (float*)alloc((size_t)8192 * 10 * 4);
    float* S0q    = (float*)alloc((size_t)1200 * 512 * 4);
    float* dAb    = (float*)alloc((size_t)8192 * 8 * QP * 4);
    float* dtBb   = (float*)alloc((size_t)8192 * 8 * QP * 4);
    float* Cmb    = (float*)alloc((size_t)8192 * QP * 4);
    float* segd   = (float*)alloc((size_t)BB * NSEG * 8 * QP * 4);
    float* Sloc   = (float*)alloc((size_t)2 * NSEG * 32 * QP * 64 * 4);
    float* Sin    = (float*)alloc((size_t)2 * NSEG * 32 * QP * 64 * 4);
    float* yfb    = (float*)alloc((size_t)8192 * 512 * 4);
    float* ybb    = (float*)alloc((size_t)8192 * 512 * 4);
    float* Savg   = (float*)alloc((size_t)32 * QP * 64 * 4);
    ushort_t* ink_h  = (ushort_t*)alloc((size_t)2097152 * 2);
    ushort_t* ink_l  = (ushort_t*)alloc((size_t)2097152 * 2);
    ushort_t* wk_h   = (ushort_t*)alloc((size_t)262144 * 2);
    ushort_t* wk_l   = (ushort_t*)alloc((size_t)262144 * 2);
    ushort_t* inq_h  = (ushort_t*)alloc((size_t)307200 * 2);
    ushort_t* inq_l  = (ushort_t*)alloc((size_t)307200 * 2);
    ushort_t* wq_h   = (ushort_t*)alloc((size_t)131072 * 2);
    ushort_t* wq_l   = (ushort_t*)alloc((size_t)131072 * 2);
    ushort_t* keyb_h = (ushort_t*)alloc((size_t)4194304 * 2);
    ushort_t* keyb_l = (ushort_t*)alloc((size_t)4194304 * 2);
    ushort_t* wok_h  = (ushort_t*)alloc((size_t)131072 * 2);
    ushort_t* wok_l  = (ushort_t*)alloc((size_t)131072 * 2);
    ushort_t* lsn_h  = (ushort_t*)alloc((size_t)614400 * 2);
    ushort_t* lsn_l  = (ushort_t*)alloc((size_t)614400 * 2);
    ushort_t* woq_h  = (ushort_t*)alloc((size_t)131072 * 2);
    ushort_t* woq_l  = (ushort_t*)alloc((size_t)131072 * 2);

    // Input conversions (bf16 hi/lo)
    c_split<<<8192, 256, 0, stream>>>(in_key, ink_h, ink_l, 2097152);
    c_split<<<1024, 256, 0, stream>>>(W_key, wk_h, wk_l, 262144);       // rows 0..1023
    c_split<<<1200, 256, 0, stream>>>(in_query, inq_h, inq_l, 307200);
    c_split<<<512, 256, 0, stream>>>(W_query, wq_h, wq_l, 131072);
    c_split<<<512, 256, 0, stream>>>(W_out_key, wok_h, wok_l, 131072);
    c_split<<<512, 256, 0, stream>>>(W_out_query, woq_h, woq_l, 131072);

    // Projections
    gemm_bf16s<<<dim3(16, 64), 256, 0, stream>>>(ink_h, ink_l, wk_h, wk_l, zx, 8192, 1024, 256);
    k1b_bias<<<2048, 256, 0, stream>>>(in_key, W_key, bias10);
    gemm_bf16s<<<dim3(8, 10), 256, 0, stream>>>(inq_h, inq_l, wq_h, wq_l, S0q, 1200, 512, 256);

    // dist -> dA, dtB, Cm
    k2_dist<<<9600, 256, 0, stream>>>(dist, bias10, W_bc, W_dt, dt_bias, A_log, dAb, dtBb, Cmb);
    k2b_segdecay<<<640, 256, 0, stream>>>(dAb, segd);

    // segmented bidirectional scan: single march + combine + MFMA correction
    pass_ac<<<dim3(NSEG, 32, 2), 512, 0, stream>>>(dAb, dtBb, Cmb, zx, Sloc, yfb, ybb);
    pass_b<<<2560, 256, 0, stream>>>(Sloc, segd, S0q, Sin, Savg);
    k3_corr<<<dim3(NSEG, 32, 2), 256, 0, stream>>>(dAb, Cmb, Sin, yfb, ybb);

    // out_key path (k4 writes split-bf16 directly)
    k4_gate<<<8192, 512, 0, stream>>>(yfb, ybb, zx, Dp, key_norm_w, keyb_h, keyb_l);
    gemm_bf16s<<<dim3(4, 64), 256, 0, stream>>>(keyb_h, keyb_l, wok_h, wok_l, out_key, 8192, 256, 512);

    // out_query path (k5 writes split-bf16 directly)
    k5_ln<<<1200, 512, 0, stream>>>(Savg, ln_w, ln_b, lsn_h, lsn_l);
    gemm_bf16s<<<dim3(4, 10), 256, 0, stream>>>(lsn_h, lsn_l, woq_h, woq_l, out_query, 1200, 256, 512);
}